// Round 9
// baseline (1233.167 us; speedup 1.0000x reference)
//
#include <hip/hip_runtime.h>
#include <math.h>

#define H    512
#define TH3  1536
#define GRID 224

// ---------------- workspace layout (float offsets), P=3 parities ----------------
#define WS_STATE(l,p) ((size_t)((l)*3+(p)) * 8192)          // 0 .. 73728
#define WS_A1(p)      ((size_t)73728 + (size_t)(p)*8192)    // 73728 .. 98304
#define WS_ATOMS      ((size_t)98304)                        // 98304 .. 884736
#define WS_E          ((size_t)884736)                       // e_i/e_j buffers
// flags u32[256] at WS_E during k_gru; k_eij overwrites the region afterwards.

__device__ __forceinline__ float sigm_(float x) { return 1.0f / (1.0f + expf(-x)); }

// ---- LSB stamping: freshness tag lives in the data mantissa LSB ----
__device__ __forceinline__ float stampf(float x, unsigned b) {
    return __uint_as_float((__float_as_uint(x) & ~1u) | b);
}
__device__ __forceinline__ int lsb4ok(float4 v, unsigned e) {
    return ((__float_as_uint(v.x) & 1u) == e) & ((__float_as_uint(v.y) & 1u) == e) &
           ((__float_as_uint(v.z) & 1u) == e) & ((__float_as_uint(v.w) & 1u) == e);
}

// ---- coherent memory helpers (sc0 sc1) ----
__device__ __forceinline__ void ld_coh4(const float* p0, const float* p1,
                                        const float* p2, const float* p3,
                                        float4& a, float4& b, float4& c, float4& d)
{
    asm volatile(
        "global_load_dwordx4 %0, %4, off sc0 sc1\n\t"
        "global_load_dwordx4 %1, %5, off sc0 sc1\n\t"
        "global_load_dwordx4 %2, %6, off sc0 sc1\n\t"
        "global_load_dwordx4 %3, %7, off sc0 sc1\n\t"
        "s_waitcnt vmcnt(0)"
        : "=&v"(a), "=&v"(b), "=&v"(c), "=&v"(d)
        : "v"(p0), "v"(p1), "v"(p2), "v"(p3)
        : "memory");
}

__device__ __forceinline__ void ld_coh8(const float* p0, const float* p1,
                                        const float* p2, const float* p3,
                                        const float* p4, const float* p5,
                                        const float* p6, const float* p7,
                                        float4& a, float4& b, float4& c, float4& d,
                                        float4& e, float4& f, float4& g, float4& h)
{
    asm volatile(
        "global_load_dwordx4 %0, %8, off sc0 sc1\n\t"
        "global_load_dwordx4 %1, %9, off sc0 sc1\n\t"
        "global_load_dwordx4 %2, %10, off sc0 sc1\n\t"
        "global_load_dwordx4 %3, %11, off sc0 sc1\n\t"
        "global_load_dwordx4 %4, %12, off sc0 sc1\n\t"
        "global_load_dwordx4 %5, %13, off sc0 sc1\n\t"
        "global_load_dwordx4 %6, %14, off sc0 sc1\n\t"
        "global_load_dwordx4 %7, %15, off sc0 sc1\n\t"
        "s_waitcnt vmcnt(0)"
        : "=&v"(a), "=&v"(b), "=&v"(c), "=&v"(d),
          "=&v"(e), "=&v"(f), "=&v"(g), "=&v"(h)
        : "v"(p0), "v"(p1), "v"(p2), "v"(p3),
          "v"(p4), "v"(p5), "v"(p6), "v"(p7)
        : "memory");
}

// waitcnt + sched_barrier (rule-#18): pins subsequent register-only consumers
// below the wait; no tied operands (gfx950 rejects tied 128-bit inline asm).
__device__ __forceinline__ void vm_wait0() {
    asm volatile("s_waitcnt vmcnt(0)" ::: "memory");
    __builtin_amdgcn_sched_barrier(0);
}

// ---- R9 EXPERIMENT: agent-scope release fence after state publication ----
// Theory: sc0sc1 stores (and R7's unscoped atomics) land DIRTY in the local
// XCD's L2; cross-XCD visibility waits ~3.6us for lazy writeback. An agent
// release fence lowers to s_waitcnt vmcnt(0) + buffer_wbl2 sc1 (eager
// device-scope L2 writeback) -> tau_vis should collapse to ~1 RT.
__device__ __forceinline__ void rel_fence() {
    __builtin_amdgcn_fence(__ATOMIC_RELEASE, "agent");
}

__device__ __forceinline__ void st_coh1(float* p, float v) {
    asm volatile("global_store_dword %0, %1, off sc0 sc1" :: "v"(p), "v"(v) : "memory");
}

__device__ __forceinline__ void ld_coh_u32x2(const unsigned* p0, const unsigned* p1,
                                             unsigned& a, unsigned& b)
{
    asm volatile(
        "global_load_dword %0, %2, off sc0 sc1\n\t"
        "global_load_dword %1, %3, off sc0 sc1\n\t"
        "s_waitcnt vmcnt(0)"
        : "=&v"(a), "=&v"(b)
        : "v"(p0), "v"(p1)
        : "memory");
}

// issue-only flag loads: fly across the stage; its vmcnt(0) drains them.
__device__ __forceinline__ void ld_coh_u32x2_issue(const unsigned* p0, const unsigned* p1,
                                                   unsigned& a, unsigned& b)
{
    asm volatile(
        "global_load_dword %0, %2, off sc0 sc1\n\t"
        "global_load_dword %1, %3, off sc0 sc1"
        : "=&v"(a), "=&v"(b)
        : "v"(p0), "v"(p1)
        : "memory");
}

__device__ __forceinline__ void st_coh_u32(unsigned* p, unsigned v) {
    asm volatile("global_store_dword %0, %1, off sc0 sc1" :: "v"(p), "v"(v) : "memory");
}

// ---- cross-lane helpers: DPP (VALU) for xor1/xor2/xor8, ds_swizzle for xor4/xor16 ----
template<int CTRL>
__device__ __forceinline__ float dppmov(float v) {
    return __int_as_float(__builtin_amdgcn_update_dpp(
        0, __float_as_int(v), CTRL, 0xF, 0xF, true));
}
#define DPP_XOR1 0xB1   // quad_perm(1,0,3,2)
#define DPP_XOR2 0x4E   // quad_perm(2,3,0,1)
#define DPP_XOR8 0x128  // row_ror:8  (== xor8 within 16)

template<int PAT>
__device__ __forceinline__ float swzf(float v) {
    return __int_as_float(__builtin_amdgcn_ds_swizzle(__float_as_int(v), PAT));
}
#define SWZ_XOR4  0x101F
#define SWZ_XOR16 0x401F

// ---------------- h_init: z @ W_l2h + b_l2h, LSB-stamped parities ----------------
// R9: 256 blocks, 8-way K-split + LDS reduce (was 32 blocks x 512-deep serial
// dot, latency-bound). Same output layout/values.
// Skews 0/2/4/5/6 => first reads: STATE0 real@p2, STATE1 real@p1, STATE2 real@p0,
// all with expected LSB 1; junk parities carry the complement of their first
// expected LSB so consumers spin until the first fresh write lands.
extern "C" __global__ __launch_bounds__(256)
void k_init(const float* __restrict__ z, const float* __restrict__ Wl2h,
            const float* __restrict__ bl2h, float* __restrict__ ws)
{
    __shared__ float part[8][2][16];
    if (blockIdx.x == 0)
        ((unsigned*)(ws + WS_E))[threadIdx.x] = 0u;   // flags[0..255]
    const int t  = threadIdx.x;
    const int b  = t & 15, j2 = (t >> 4) & 1, kq = t >> 5;   // kq 0..7
    const int j  = blockIdx.x * 2 + j2;
    float acc = 0.f;
    const int k0 = kq * 64;
    #pragma unroll 8
    for (int k = 0; k < 64; ++k)
        acc += z[b * H + k0 + k] * Wl2h[(size_t)(k0 + k) * H + j];
    part[kq][j2][b] = acc;
    __syncthreads();
    if (t < 32) {
        float a = bl2h[j];
        #pragma unroll
        for (int q = 0; q < 8; ++q) a += part[q][j2][b];

        const int preh[3][3] = { { 1, 0, -1 },
                                 { 0, -1, 1 },
                                 { -1, 1, 0 } };
        #pragma unroll
        for (int l = 0; l < 3; ++l)
            #pragma unroll
            for (int p = 0; p < 3; ++p) {
                float v = (preh[l][p] < 0) ? stampf(a, 1u)
                                           : __uint_as_float((unsigned)preh[l][p]);
                ws[WS_STATE(l, p) + j * 16 + b] = v;
            }
        const unsigned preA1[3] = { 1u, 0u, 0u };
        #pragma unroll
        for (int p = 0; p < 3; ++p)
            ws[WS_A1(p) + j * 16 + b] = __uint_as_float(preA1[p]);
    }
}

// ---------------- persistent pipelined GRU + MLP decoder ----------------
// 224 blocks, 1/CU by LDS (126 KB). Stage map (skew in parens):
//   job0 (0): bid   0..63,  8 cols, h@W_hh K-split over cs&1    -> STATE0
//   job1 (2): bid  64..127, 8 cols, phase A x@W_ih / B h@W_hh   -> STATE1
//   job2 (4): bid 128..191, 8 cols, phase A / B                 -> STATE2
//   job3 (5): bid 192..207, 32 cols, relu(h2@Wa1+ba1)           -> A1
//   job4 (6): bid 208..223, 32 cols, a1@Wa2+ba2                 -> atoms
// R6 structure (proven 556us) + R9: rel_fence after each state publication
// to force eager L2 writeback (tau_vis experiment).
__global__ __launch_bounds__(512, 2)
void k_gru(const float* __restrict__ W_ih, const float* __restrict__ W_hh,
           const float* __restrict__ b_ih, const float* __restrict__ b_hh,
           const float* __restrict__ Wa1,  const float* __restrict__ ba1,
           const float* __restrict__ Wa2,  const float* __restrict__ ba2,
           float* __restrict__ ws)
{
    __shared__ float sx[10240];
    __shared__ float sx2[10240];
    __shared__ float sh[10240];
    __shared__ float red[1536];
    unsigned* flags = (unsigned*)(ws + WS_E);

    const int bid = blockIdx.x;
    const int tid = threadIdx.x;

    int job, jbase;
    if      (bid < 64)  { job = 0; jbase = bid * 8; }
    else if (bid < 128) { job = 1; jbase = (bid - 64) * 8; }
    else if (bid < 192) { job = 2; jbase = (bid - 128) * 8; }
    else if (bid < 208) { job = 3; jbase = (bid - 192) * 32; }
    else                { job = 4; jbase = (bid - 208) * 32; }

    const int ks = tid & 31;
    const int cs = tid >> 6;

    // ---- anti-dep poll set: consumers of the buffer this stage writes ----
    int rs0, rc0;
    if      (job == 0) { rs0 = 0;   rc0 = 128; }
    else if (job == 1) { rs0 = 64;  rc0 = 128; }
    else if (job == 2) { rs0 = 128; rc0 = 80;  }
    else if (job == 3) { rs0 = 208; rc0 = 16;  }
    else               { rs0 = 0;   rc0 = 0;   }
    int fidl[2];
    #pragma unroll
    for (int e = 0; e < 2; ++e) {
        int idx = (tid & 63) + e * 64;
        fidl[e] = (idx < rc0) ? rs0 + idx : bid;   // own flag trivially passes
    }

    // ---- one-time weight preload into registers ----
    float w[6][16];
    if (job <= 2) {
        const int khalf = cs & 1, cpair = cs >> 1;
        const int colbase = jbase + cpair * 2;
        const float* WB = W_hh + (size_t)job * H * TH3;
        const float* WA = W_ih + (size_t)job * H * TH3;
        #pragma unroll
        for (int f = 0; f < 6; ++f) {
            int g = f >> 1, c = f & 1;
            #pragma unroll
            for (int kk = 0; kk < 8; ++kk) {
                size_t ro = (size_t)(khalf * 256 + kk * 32 + ks) * TH3 + g * 512 + colbase + c;
                w[f][8 + kk] = WB[ro];
                if (job != 0) w[f][kk] = WA[ro];
            }
        }
    } else {
        const float* base = (job == 3) ? Wa1 : Wa2;
        const int colbase = jbase + cs * 4;
        #pragma unroll
        for (int f = 0; f < 4; ++f)
            #pragma unroll
            for (int kk = 0; kk < 16; ++kk)
                w[f][kk] = base[(size_t)(kk * 32 + ks) * H + colbase + f];
    }

    // ---- epilogue constants (biases + running h for own cols) ----
    float c_bi0 = 0, c_bi1 = 0, c_bi2 = 0, c_bh0 = 0, c_bh1 = 0, c_bh2 = 0;
    float hp = 0.f, c_ba = 0.f;
    if (job <= 2) {
        if (tid < 128) {
            int b = tid & 15, j2 = tid >> 4, jc = jbase + j2;
            const float* bi  = b_ih + (size_t)job * TH3;
            const float* bhh = b_hh + (size_t)job * TH3;
            c_bi0 = bi[jc]; c_bi1 = bi[512 + jc]; c_bi2 = bi[1024 + jc];
            c_bh0 = bhh[jc]; c_bh1 = bhh[512 + jc]; c_bh2 = bhh[1024 + jc];
            const int hpp = (job == 0) ? 2 : (job == 1) ? 1 : 0;  // init-real parity
            hp = ws[WS_STATE(job, hpp) + jc * 16 + b];
        }
    } else if (job == 3) {
        c_ba = ba1[jbase + (tid >> 4)];
    } else {
        c_ba = ba2[jbase + (tid & 31)];
    }

    // ---- verify+stage one 32KB [512][16] buffer into LDS [512][20] (fused) ----
    auto stage32k = [&](const float* src, unsigned eb, float* dst) {
        const int k0 = tid >> 2, q4 = (tid & 3) * 4;
        float4 a, b, c, d;
        for (;;) {
            ld_coh4(src + 4 * tid, src + 4 * (tid + 512),
                    src + 4 * (tid + 1024), src + 4 * (tid + 1536), a, b, c, d);
            if (__all(lsb4ok(a, eb) & lsb4ok(b, eb) & lsb4ok(c, eb) & lsb4ok(d, eb)))
                break;
            __builtin_amdgcn_s_sleep(1);
        }
        *(float4*)&dst[(k0      ) * 20 + q4] = a;
        *(float4*)&dst[(k0 + 128) * 20 + q4] = b;
        *(float4*)&dst[(k0 + 256) * 20 + q4] = c;
        *(float4*)&dst[(k0 + 384) * 20 + q4] = d;
    };

    // ---- verify+stage TWO 32KB buffers in ONE round trip (jobs 1/2) ----
    // srcH = own h (this step, may spin); srcX = next-step x (1 step old, fresh)
    auto stage64k = [&](const float* srcH, const float* srcX, unsigned eb,
                        float* dstH, float* dstX) {
        const int k0 = tid >> 2, q4 = (tid & 3) * 4;
        float4 xa, xb, xc, xd, ha, hb, hc, hd;
        for (;;) {
            ld_coh8(srcX + 4 * tid, srcX + 4 * (tid + 512),
                    srcX + 4 * (tid + 1024), srcX + 4 * (tid + 1536),
                    srcH + 4 * tid, srcH + 4 * (tid + 512),
                    srcH + 4 * (tid + 1024), srcH + 4 * (tid + 1536),
                    xa, xb, xc, xd, ha, hb, hc, hd);
            int ok = lsb4ok(xa, eb) & lsb4ok(xb, eb) & lsb4ok(xc, eb) & lsb4ok(xd, eb) &
                     lsb4ok(ha, eb) & lsb4ok(hb, eb) & lsb4ok(hc, eb) & lsb4ok(hd, eb);
            if (__all(ok)) break;
            __builtin_amdgcn_s_sleep(1);
        }
        *(float4*)&dstX[(k0      ) * 20 + q4] = xa;
        *(float4*)&dstX[(k0 + 128) * 20 + q4] = xb;
        *(float4*)&dstX[(k0 + 256) * 20 + q4] = xc;
        *(float4*)&dstX[(k0 + 384) * 20 + q4] = xd;
        *(float4*)&dstH[(k0      ) * 20 + q4] = ha;
        *(float4*)&dstH[(k0 + 128) * 20 + q4] = hb;
        *(float4*)&dstH[(k0 + 256) * 20 + q4] = hc;
        *(float4*)&dstH[(k0 + 384) * 20 + q4] = hd;
    };

    // ---- speculative flag check: values were issued at step top and drained
    //      by the stage's vmcnt(0); compare is free. Spin only on stale miss.
    auto flagchk = [&](unsigned fv0, unsigned fv1, unsigned lim) {
        if (!__all((int)((fv0 >= lim) & (fv1 >= lim)))) {
            for (;;) {
                __builtin_amdgcn_s_sleep(1);
                unsigned v0, v1;
                ld_coh_u32x2(&flags[fidl[0]], &flags[fidl[1]], v0, v1);
                if (__all((int)((v0 >= lim) & (v1 >= lim)))) break;
            }
        }
    };

    // ---- K-split 6-gate matvec + reduce-scatter (jobs 0..2) ----
    auto mv6 = [&](const float* arr, int wo, int redbase) {
        const int qh = (tid >> 5) & 1;
        const int rowoff = 8 * qh;
        const bool b0 = (ks & 1), b1 = (ks & 2), b3 = (ks & 8), b4 = (ks & 16);
        const float* base = arr + (cs & 1) * (256 * 20);
        float acc[6][8];
        #pragma unroll
        for (int f = 0; f < 6; ++f)
            #pragma unroll
            for (int i = 0; i < 8; ++i) acc[f][i] = 0.f;
        #pragma unroll
        for (int kk = 0; kk < 8; ++kk) {
            const float* p = base + (kk * 32 + ks) * 20 + rowoff;
            float4 v0 = *(const float4*)p;
            float4 v1 = *(const float4*)(p + 4);
            #pragma unroll
            for (int f = 0; f < 6; ++f) {
                float wv = w[f][wo + kk];
                acc[f][0] += wv * v0.x; acc[f][1] += wv * v0.y;
                acc[f][2] += wv * v0.z; acc[f][3] += wv * v0.w;
                acc[f][4] += wv * v1.x; acc[f][5] += wv * v1.y;
                acc[f][6] += wv * v1.z; acc[f][7] += wv * v1.w;
            }
        }
        float a[6];
        #pragma unroll
        for (int f = 0; f < 6; ++f) {
            float t[4];
            #pragma unroll
            for (int j = 0; j < 4; ++j) {
                float give = b0 ? acc[f][j] : acc[f][j + 4];
                float recv = dppmov<DPP_XOR1>(give);
                float keep = b0 ? acc[f][j + 4] : acc[f][j];
                t[j] = keep + recv;
            }
            float u[2];
            #pragma unroll
            for (int j = 0; j < 2; ++j) {
                float give = b1 ? t[j] : t[j + 2];
                float recv = dppmov<DPP_XOR2>(give);
                float keep = b1 ? t[j + 2] : t[j];
                u[j] = keep + recv;
            }
            float give = b3 ? u[0] : u[1];
            float recv = dppmov<DPP_XOR8>(give);
            float keep = b3 ? u[1] : u[0];
            a[f] = keep + recv;
        }
        #pragma unroll
        for (int f = 0; f < 6; ++f) a[f] += swzf<SWZ_XOR4>(a[f]);
        float r[3];
        #pragma unroll
        for (int i = 0; i < 3; ++i) {
            float give = b4 ? a[i] : a[i + 3];
            float recv = swzf<SWZ_XOR16>(give);
            float keep = b4 ? a[i + 3] : a[i];
            r[i] = keep + recv;
        }
        if (!(ks & 4)) {
            int bl = ((ks & 1) << 2) | (ks & 2) | ((ks >> 3) & 1);
            int bb = ((tid >> 5) & 1) * 8 + bl;
            int fb3 = ((ks >> 4) & 1) * 3;
            #pragma unroll
            for (int i = 0; i < 3; ++i) {
                int f = fb3 + i, g = f >> 1, c = f & 1;
                red[redbase + (cs & 1) * 384 + g * 128 + ((cs >> 1) * 2 + c) * 16 + bb] = r[i];
            }
        }
    };

    // ---- 4-col matvec + reduce-scatter (jobs 3/4, 32 cols/block, 16 kk) ----
    auto mv4 = [&](const float* arr) {
        const int qh = (tid >> 5) & 1;
        const int rowoff = 8 * qh;
        const bool b0 = (ks & 1), b1 = (ks & 2), b3 = (ks & 8), b4 = (ks & 16);
        float acc[4][8];
        #pragma unroll
        for (int f = 0; f < 4; ++f)
            #pragma unroll
            for (int i = 0; i < 8; ++i) acc[f][i] = 0.f;
        #pragma unroll
        for (int kk = 0; kk < 16; ++kk) {
            const float* p = arr + (kk * 32 + ks) * 20 + rowoff;
            float4 v0 = *(const float4*)p;
            float4 v1 = *(const float4*)(p + 4);
            #pragma unroll
            for (int f = 0; f < 4; ++f) {
                float wv = w[f][kk];
                acc[f][0] += wv * v0.x; acc[f][1] += wv * v0.y;
                acc[f][2] += wv * v0.z; acc[f][3] += wv * v0.w;
                acc[f][4] += wv * v1.x; acc[f][5] += wv * v1.y;
                acc[f][6] += wv * v1.z; acc[f][7] += wv * v1.w;
            }
        }
        float a[4];
        #pragma unroll
        for (int f = 0; f < 4; ++f) {
            float t[4];
            #pragma unroll
            for (int j = 0; j < 4; ++j) {
                float give = b0 ? acc[f][j] : acc[f][j + 4];
                float recv = dppmov<DPP_XOR1>(give);
                float keep = b0 ? acc[f][j + 4] : acc[f][j];
                t[j] = keep + recv;
            }
            float u[2];
            #pragma unroll
            for (int j = 0; j < 2; ++j) {
                float give = b1 ? t[j] : t[j + 2];
                float recv = dppmov<DPP_XOR2>(give);
                float keep = b1 ? t[j + 2] : t[j];
                u[j] = keep + recv;
            }
            float give = b3 ? u[0] : u[1];
            float recv = dppmov<DPP_XOR8>(give);
            float keep = b3 ? u[1] : u[0];
            a[f] = keep + recv;
        }
        #pragma unroll
        for (int f = 0; f < 4; ++f) a[f] += swzf<SWZ_XOR4>(a[f]);
        float r[2];
        #pragma unroll
        for (int i = 0; i < 2; ++i) {
            float give = b4 ? a[i] : a[i + 2];
            float recv = swzf<SWZ_XOR16>(give);
            float keep = b4 ? a[i + 2] : a[i];
            r[i] = keep + recv;
        }
        if (!(ks & 4)) {
            int bl = ((ks & 1) << 2) | (ks & 2) | ((ks >> 3) & 1);
            int bb = ((tid >> 5) & 1) * 8 + bl;
            int f2 = ((ks >> 4) & 1) * 2;
            #pragma unroll
            for (int i = 0; i < 2; ++i)
                red[(cs * 4 + f2 + i) * 16 + bb] = r[i];
        }
    };

    for (int s = 0; s < 102; ++s) {
        const int rp = (s + 2) % 3, wp = s % 3;      // rp = (s-1)%3: 1-back parity
        const unsigned expb = (unsigned)((s + 1) & 1);
        const unsigned myb  = (unsigned)(s & 1);
        int act;
        if      (job == 0) act = (s <= 95);
        else if (job == 1) act = (s >= 2 && s <= 97);
        else if (job == 2) act = (s >= 4 && s <= 99);
        else if (job == 3) act = (s >= 5 && s <= 100);
        else               act = (s >= 6 && s <= 101);
        // jobs 1/2: stage next-step x during this step's phase-B round?
        // x consumed at steps s0..s0+95  ->  staged at s in [s0-1, s0+94]
        const int s0 = (job == 1) ? 2 : 4;
        const int dox = (job == 1 || job == 2) && (s >= s0 - 1) && (s <= s0 + 94);
        float* rbuf = (s & 1) ? sx2 : sx;            // x read at step s
        float* wbuf = (s & 1) ? sx : sx2;            // x staged for step s+1
        bool posted = false;

        if (act) {
            // ---- speculative anti-dep: issue 2 flag dwords, no wait ----
            unsigned fv0 = 0xFFFFFFFFu, fv1 = 0xFFFFFFFFu;
            const bool needchk = (tid < 64) && (s >= 2);
            if (needchk)
                ld_coh_u32x2_issue(&flags[fidl[0]], &flags[fidl[1]], fv0, fv1);

            if (job == 1 || job == 2) {
                const float* srcH = ws + WS_STATE(job, rp);
                const float* srcX = ws + WS_STATE(job - 1, rp);
                // phase A: x @ W_ih from rbuf (staged during step s-1, no wait)
                mv6(rbuf, 0, 0);
                // phase B: fetch own h (+ next-step x) — fused detect (R3 path)
                if (dox)
                    stage64k(srcH, srcX, expb, sh, wbuf);
                else
                    stage32k(srcH, expb, sh);
                // flag check: drained by stage's vmcnt(0); compare ~free
                if (needchk) { vm_wait0(); flagchk(fv0, fv1, (unsigned)(s - 1)); }
                __syncthreads();
                // early anti-dep release: all coherent reads complete here
                if (tid == 0) st_coh_u32(&flags[bid], (unsigned)(s + 1));
                posted = true;
                mv6(sh, 8, 768);
                __syncthreads();
                if (tid < 128) {
                    int b = tid & 15, jc = jbase + (tid >> 4);
                    int o = tid;
                    float gi0 = red[o]        + red[384 + o];
                    float gi1 = red[128 + o]  + red[512 + o];
                    float gi2 = red[256 + o]  + red[640 + o];
                    float gh0 = red[768 + o]  + red[1152 + o];
                    float gh1 = red[896 + o]  + red[1280 + o];
                    float gh2 = red[1024 + o] + red[1408 + o];
                    float r  = sigm_(gi0 + c_bi0 + gh0 + c_bh0);
                    float zg = sigm_(gi1 + c_bi1 + gh1 + c_bh1);
                    float n  = tanhf(gi2 + c_bi2 + r * (gh2 + c_bh2));
                    float hn = (1.f - zg) * n + zg * hp;
                    hp = hn;
                    st_coh1(&ws[WS_STATE(job, wp) + jc * 16 + b], stampf(hn, myb));
                    rel_fence();   // eager L2 writeback of the published state
                }
            } else if (job == 0) {
                stage32k(ws + WS_STATE(0, rp), expb, sx);
                if (needchk) { vm_wait0(); flagchk(fv0, fv1, (unsigned)(s - 1)); }
                __syncthreads();
                if (tid == 0) st_coh_u32(&flags[bid], (unsigned)(s + 1));
                posted = true;
                mv6(sx, 8, 768);
                __syncthreads();
                if (tid < 128) {
                    int b = tid & 15, jc = jbase + (tid >> 4);
                    int o = tid;
                    float g0 = red[768 + o]  + red[1152 + o];
                    float g1 = red[896 + o]  + red[1280 + o];
                    float g2 = red[1024 + o] + red[1408 + o];
                    float r  = sigm_(c_bi0 + g0 + c_bh0);
                    float zg = sigm_(c_bi1 + g1 + c_bh1);
                    float n  = tanhf(c_bi2 + r * (g2 + c_bh2));
                    float hn = (1.f - zg) * n + zg * hp;
                    hp = hn;
                    st_coh1(&ws[WS_STATE(0, wp) + jc * 16 + b], stampf(hn, myb));
                    rel_fence();   // eager L2 writeback of the published state
                }
            } else {
                const float* srcp = (job == 3) ? (ws + WS_STATE(2, rp))
                                               : (ws + WS_A1(rp));
                stage32k(srcp, expb, sx);
                if (needchk) { vm_wait0(); flagchk(fv0, fv1, (unsigned)(s - 1)); }
                __syncthreads();
                if (tid == 0) st_coh_u32(&flags[bid], (unsigned)(s + 1));
                posted = true;
                mv4(sx);
                __syncthreads();
                if (job == 3) {
                    int b = tid & 15, j2 = tid >> 4, jc = jbase + j2;
                    float v = red[j2 * 16 + b] + c_ba;
                    st_coh1(&ws[WS_A1(wp) + jc * 16 + b], stampf(fmaxf(v, 0.f), myb));
                    rel_fence();   // eager L2 writeback of the published state
                } else {
                    int j2 = tid & 31, b = tid >> 5, jc = jbase + j2;
                    float v = red[j2 * 16 + b] + c_ba;
                    ws[WS_ATOMS + ((size_t)(s - 6) * 16 + b) * H + jc] = v;
                }
            }
        } else if (dox) {
            // pre-loop x prestage (s == s0-1 only): fill wbuf for first phase A
            stage32k(ws + WS_STATE(job - 1, rp), expb, wbuf);
        }

        // ---- bottom barrier protects red[]/LDS reuse and barrier pairing;
        //      post flag here only if not already released this step ----
        __syncthreads();
        if (!posted && tid == 0) st_coh_u32(&flags[bid], (unsigned)(s + 1));
    }
}

// ---------------- fused tail-1: e_i/e_j GEMM (blocks 0..1535) + argmax (1536..1631) ----
extern "C" __global__ __launch_bounds__(256)
void k_tail1(const float* __restrict__ Wb1, const float* __restrict__ bb1,
             float* __restrict__ ws, float* __restrict__ out)
{
    __shared__ float aT[8192];                 // [k][b16], 32 KB (eij branch only)
    const int bid = blockIdx.x;
    const int tid = threadIdx.x;
    const float* atoms = ws + WS_ATOMS;

    if (bid >= 1536) {
        // ---- argmax over logits (first-max-wins) ----
        const int t = bid - 1536;              // 0..95
        const int wv = tid >> 6, lane = tid & 63;
        for (int b = wv; b < 16; b += 4) {
            const float* row = atoms + ((size_t)t * 16 + b) * H;
            float mx = -3.4028235e38f; int mi = 0;
            #pragma unroll
            for (int c = 0; c < 8; ++c) {
                int idx = lane + c * 64;
                float v = row[idx];
                if (v > mx) { mx = v; mi = idx; }
            }
            #pragma unroll
            for (int off = 32; off >= 1; off >>= 1) {
                float omx = __shfl_down(mx, off);
                int   omi = __shfl_down(mi, off);
                if (omx > mx || (omx == mx && omi < mi)) { mx = omx; mi = omi; }
            }
            if (lane == 0) out[b * 96 + t] = (float)mi;
        }
        return;
    }

    // ---- e_i / e_j = atoms @ Wb1 halves, tiled (16 rows reuse) ----
    const int t = bid >> 4, m = (bid >> 3) & 1, ct = bid & 7;
    for (int f = tid; f < 2048; f += 256) {    // transpose-stage A tile
        int b = f >> 7, kq = f & 127;
        float4 v = ((const float4*)(atoms + ((size_t)(t * 16 + b)) * H))[kq];
        aT[(kq * 4 + 0) * 16 + b] = v.x;
        aT[(kq * 4 + 1) * 16 + b] = v.y;
        aT[(kq * 4 + 2) * 16 + b] = v.z;
        aT[(kq * 4 + 3) * 16 + b] = v.w;
    }
    __syncthreads();
    const int c = tid & 63, rq = tid >> 6;
    const int col = ct * 64 + c;
    const float* Wp = Wb1 + (size_t)m * H * H + col;
    float a0 = 0, a1 = 0, a2 = 0, a3 = 0;
    #pragma unroll 8
    for (int k = 0; k < 512; ++k) {
        float  wv = Wp[(size_t)k * H];
        float4 av = *(const float4*)&aT[k * 16 + rq * 4];
        a0 += av.x * wv; a1 += av.y * wv; a2 += av.z * wv; a3 += av.w * wv;
    }
    float bb = (m == 0) ? bb1[col] : 0.f;
    a0 += bb; a1 += bb; a2 += bb; a3 += bb;
    float* eb = ws + WS_E + (size_t)(m * 16) * 96 * H;
    eb[((size_t)(rq * 4 + 0) * 96 + t) * H + col] = a0;
    eb[((size_t)(rq * 4 + 1) * 96 + t) * H + col] = a1;
    eb[((size_t)(rq * 4 + 2) * 96 + t) * H + col] = a2;
    eb[((size_t)(rq * 4 + 3) * 96 + t) * H + col] = a3;
}

// ---------------- fused edge MLP: relu(e_i + e_j) @ Wb2 + bb2, diag zeroed ----
extern "C" __global__ __launch_bounds__(256)
void k_edge(const float* __restrict__ Wb2, const float* __restrict__ bb2,
            const float* __restrict__ ws, float* __restrict__ out)
{
    __shared__ float ls[32][260];
    __shared__ float wsm[2048];
    const int bid = blockIdx.x;                // b*36 + it*6 + jt
    const int b = bid / 36, r6 = bid % 36, it = r6 / 6, jt = r6 % 6;
    const int tid = threadIdx.x;
    const int ip = tid & 15, jp = tid >> 4;
    float acc0 = 0, acc1 = 0, acc2 = 0, acc3 = 0;

    for (int f = tid; f < 2048; f += 256)      // Wb2 -> LDS (one-time)
        wsm[f] = Wb2[f];

    for (int ph = 0; ph < 2; ++ph) {
        __syncthreads();
        for (int f = tid; f < 2048; f += 256) {
            int r = f >> 6, c4 = f & 63;
            const float* src = (r < 16)
                ? ws + WS_E + ((size_t)b * 96 + it * 16 + r) * H
                : ws + WS_E + ((size_t)(16 + b) * 96 + jt * 16 + (r - 16)) * H;
            float4 v = *(const float4*)(src + ph * 256 + c4 * 4);
            *(float4*)&ls[r][c4 * 4] = v;
        }
        __syncthreads();
        const float* wb = &wsm[ph * 1024];
        #pragma unroll 2
        for (int hh = 0; hh < 256; hh += 4) {
            float4 ei = *(const float4*)&ls[ip][hh];
            float4 ej = *(const float4*)&ls[16 + jp][hh];
            float4 w0 = *(const float4*)(wb + (size_t)hh * 4);
            float4 w1 = *(const float4*)(wb + (size_t)hh * 4 + 4);
            float4 w2 = *(const float4*)(wb + (size_t)hh * 4 + 8);
            float4 w3 = *(const float4*)(wb + (size_t)hh * 4 + 12);
            float v;
            v = fmaxf(ei.x + ej.x, 0.f); acc0 += v * w0.x; acc1 += v * w0.y; acc2 += v * w0.z; acc3 += v * w0.w;
            v = fmaxf(ei.y + ej.y, 0.f); acc0 += v * w1.x; acc1 += v * w1.y; acc2 += v * w1.z; acc3 += v * w1.w;
            v = fmaxf(ei.z + ej.z, 0.f); acc0 += v * w2.x; acc1 += v * w2.y; acc2 += v * w2.z; acc3 += v * w2.w;
            v = fmaxf(ei.w + ej.w, 0.f); acc0 += v * w3.x; acc1 += v * w3.y; acc2 += v * w3.z; acc3 += v * w3.w;
        }
    }
    const int i = it * 16 + ip, j = jt * 16 + jp;
    float4 o;
    if (i == j) { o.x = 0.f; o.y = 0.f; o.z = 0.f; o.w = 0.f; }
    else { o.x = acc0 + bb2[0]; o.y = acc1 + bb2[1]; o.z = acc2 + bb2[2]; o.w = acc3 + bb2[3]; }
    *(float4*)(out + 1536 + (((size_t)b * 96 + i) * 96 + j) * 4) = o;
}

// ---------------- host ----------------
extern "C" void kernel_launch(void* const* d_in, const int* in_sizes, int n_in,
                              void* d_out, int out_size, void* d_ws, size_t ws_size,
                              hipStream_t stream)
{
    const float* z    = (const float*)d_in[0];
    const float* Wl2h = (const float*)d_in[1];
    const float* bl2h = (const float*)d_in[2];
    const float* W_ih = (const float*)d_in[3];
    const float* W_hh = (const float*)d_in[4];
    const float* b_ih = (const float*)d_in[5];
    const float* b_hh = (const float*)d_in[6];
    const float* Wa1  = (const float*)d_in[7];
    const float* ba1  = (const float*)d_in[8];
    const float* Wa2  = (const float*)d_in[9];
    const float* ba2  = (const float*)d_in[10];
    const float* Wb1  = (const float*)d_in[11];
    const float* bb1  = (const float*)d_in[12];
    const float* Wb2  = (const float*)d_in[13];
    const float* bb2  = (const float*)d_in[14];
    float* out = (float*)d_out;
    float* ws  = (float*)d_ws;

    hipLaunchKernelGGL(k_init, dim3(256), dim3(256), 0, stream, z, Wl2h, bl2h, ws);

    // regular launch: grid 224 (1 block/CU by LDS) is co-resident by capacity
    hipLaunchKernelGGL(k_gru, dim3(GRID), dim3(512), 0, stream,
                       W_ih, W_hh, b_ih, b_hh, Wa1, ba1, Wa2, ba2, ws);

    // fused eij + argmax (saves one launch gap)
    hipLaunchKernelGGL(k_tail1, dim3(1632), dim3(256), 0, stream, Wb1, bb1, ws, out);
    hipLaunchKernelGGL(k_edge, dim3(576), dim3(256), 0, stream, Wb2, bb2, ws, out);
}

// Round 10
// 1007.044 us; speedup vs baseline: 1.2245x; 1.2245x over previous
//
#include <hip/hip_runtime.h>
#include <math.h>

#define H    512
#define TH3  1536
#define GRID 256

// ---------------- workspace layout (float offsets), P=3 parities ----------------
#define WS_STATE(l,p) ((size_t)((l)*3+(p)) * 8192)          // 0 .. 73728
#define WS_A1(p)      ((size_t)73728 + (size_t)(p)*8192)    // 73728 .. 98304
#define WS_ATOMS      ((size_t)98304)                        // 98304 .. 884736
#define WS_E          ((size_t)884736)                       // e_i/e_j buffers
// flags u32[256] at WS_E during k_gru; k_edge-era code overwrites afterwards.

__device__ __forceinline__ float sigm_(float x) { return 1.0f / (1.0f + expf(-x)); }

// ---- LSB stamping: freshness tag lives in the data mantissa LSB ----
__device__ __forceinline__ float stampf(float x, unsigned b) {
    return __uint_as_float((__float_as_uint(x) & ~1u) | b);
}
__device__ __forceinline__ int lsb4ok(float4 v, unsigned e) {
    return ((__float_as_uint(v.x) & 1u) == e) & ((__float_as_uint(v.y) & 1u) == e) &
           ((__float_as_uint(v.z) & 1u) == e) & ((__float_as_uint(v.w) & 1u) == e);
}

// ---- coherent memory helpers (sc0 sc1) ----
__device__ __forceinline__ void ld_coh2(const float* p0, const float* p1,
                                        float4& a, float4& b)
{
    asm volatile(
        "global_load_dwordx4 %0, %2, off sc0 sc1\n\t"
        "global_load_dwordx4 %1, %3, off sc0 sc1\n\t"
        "s_waitcnt vmcnt(0)"
        : "=&v"(a), "=&v"(b)
        : "v"(p0), "v"(p1)
        : "memory");
}

__device__ __forceinline__ void ld_coh4(const float* p0, const float* p1,
                                        const float* p2, const float* p3,
                                        float4& a, float4& b, float4& c, float4& d)
{
    asm volatile(
        "global_load_dwordx4 %0, %4, off sc0 sc1\n\t"
        "global_load_dwordx4 %1, %5, off sc0 sc1\n\t"
        "global_load_dwordx4 %2, %6, off sc0 sc1\n\t"
        "global_load_dwordx4 %3, %7, off sc0 sc1\n\t"
        "s_waitcnt vmcnt(0)"
        : "=&v"(a), "=&v"(b), "=&v"(c), "=&v"(d)
        : "v"(p0), "v"(p1), "v"(p2), "v"(p3)
        : "memory");
}

__device__ __forceinline__ void ld_coh8(const float* p0, const float* p1,
                                        const float* p2, const float* p3,
                                        const float* p4, const float* p5,
                                        const float* p6, const float* p7,
                                        float4& a, float4& b, float4& c, float4& d,
                                        float4& e, float4& f, float4& g, float4& h)
{
    asm volatile(
        "global_load_dwordx4 %0, %8, off sc0 sc1\n\t"
        "global_load_dwordx4 %1, %9, off sc0 sc1\n\t"
        "global_load_dwordx4 %2, %10, off sc0 sc1\n\t"
        "global_load_dwordx4 %3, %11, off sc0 sc1\n\t"
        "global_load_dwordx4 %4, %12, off sc0 sc1\n\t"
        "global_load_dwordx4 %5, %13, off sc0 sc1\n\t"
        "global_load_dwordx4 %6, %14, off sc0 sc1\n\t"
        "global_load_dwordx4 %7, %15, off sc0 sc1\n\t"
        "s_waitcnt vmcnt(0)"
        : "=&v"(a), "=&v"(b), "=&v"(c), "=&v"(d),
          "=&v"(e), "=&v"(f), "=&v"(g), "=&v"(h)
        : "v"(p0), "v"(p1), "v"(p2), "v"(p3),
          "v"(p4), "v"(p5), "v"(p6), "v"(p7)
        : "memory");
}

// waitcnt + sched_barrier (rule-#18): pins subsequent register-only consumers
// below the wait; no tied operands (gfx950 rejects tied 128-bit inline asm).
__device__ __forceinline__ void vm_wait0() {
    asm volatile("s_waitcnt vmcnt(0)" ::: "memory");
    __builtin_amdgcn_sched_barrier(0);
}

__device__ __forceinline__ void st_coh1(float* p, float v) {
    asm volatile("global_store_dword %0, %1, off sc0 sc1" :: "v"(p), "v"(v) : "memory");
}

__device__ __forceinline__ void ld_coh_u32(const unsigned* p, unsigned& a) {
    asm volatile(
        "global_load_dword %0, %1, off sc0 sc1\n\t"
        "s_waitcnt vmcnt(0)"
        : "=&v"(a) : "v"(p) : "memory");
}

__device__ __forceinline__ void ld_coh_u32x2(const unsigned* p0, const unsigned* p1,
                                             unsigned& a, unsigned& b)
{
    asm volatile(
        "global_load_dword %0, %2, off sc0 sc1\n\t"
        "global_load_dword %1, %3, off sc0 sc1\n\t"
        "s_waitcnt vmcnt(0)"
        : "=&v"(a), "=&v"(b)
        : "v"(p0), "v"(p1)
        : "memory");
}

// issue-only flag loads: fly across the stage; its vmcnt(0) drains them.
__device__ __forceinline__ void ld_coh_u32x2_issue(const unsigned* p0, const unsigned* p1,
                                                   unsigned& a, unsigned& b)
{
    asm volatile(
        "global_load_dword %0, %2, off sc0 sc1\n\t"
        "global_load_dword %1, %3, off sc0 sc1"
        : "=&v"(a), "=&v"(b)
        : "v"(p0), "v"(p1)
        : "memory");
}

__device__ __forceinline__ void st_coh_u32(unsigned* p, unsigned v) {
    asm volatile("global_store_dword %0, %1, off sc0 sc1" :: "v"(p), "v"(v) : "memory");
}

// ---- cross-lane helpers: DPP (VALU) for xor1/xor2/xor8, ds_swizzle for xor4/xor16 ----
template<int CTRL>
__device__ __forceinline__ float dppmov(float v) {
    return __int_as_float(__builtin_amdgcn_update_dpp(
        0, __float_as_int(v), CTRL, 0xF, 0xF, true));
}
#define DPP_XOR1 0xB1   // quad_perm(1,0,3,2)
#define DPP_XOR2 0x4E   // quad_perm(2,3,0,1)
#define DPP_XOR8 0x128  // row_ror:8  (== xor8 within 16)

template<int PAT>
__device__ __forceinline__ float swzf(float v) {
    return __int_as_float(__builtin_amdgcn_ds_swizzle(__float_as_int(v), PAT));
}
#define SWZ_XOR4  0x101F
#define SWZ_XOR16 0x401F

// ---------------- h_init: z @ W_l2h + b_l2h, LSB-stamped parities ----------------
// 256 blocks, 8-way K-split + LDS reduce. Also zeroes the atoms region so its
// stamp LSBs read 0 until job4 publishes stamped (LSB=1) values.
// Skews 0/2/4/5/6 => first reads: STATE0 real@p2, STATE1 real@p1, STATE2 real@p0,
// all with expected LSB 1; junk parities carry the complement of their first
// expected LSB so consumers spin until the first fresh write lands.
extern "C" __global__ __launch_bounds__(256)
void k_init(const float* __restrict__ z, const float* __restrict__ Wl2h,
            const float* __restrict__ bl2h, float* __restrict__ ws)
{
    __shared__ float part[8][2][16];
    if (blockIdx.x == 0)
        ((unsigned*)(ws + WS_E))[threadIdx.x] = 0u;   // flags[0..255]
    const int t  = threadIdx.x;

    // zero atoms stamps: 786432 floats == 65536 threads x 12
    {
        float4 z4 = make_float4(0.f, 0.f, 0.f, 0.f);
        size_t base = WS_ATOMS + ((size_t)blockIdx.x * 256 + t) * 12;
        #pragma unroll
        for (int q = 0; q < 3; ++q)
            *(float4*)&ws[base + q * 4] = z4;
    }

    const int b  = t & 15, j2 = (t >> 4) & 1, kq = t >> 5;   // kq 0..7
    const int j  = blockIdx.x * 2 + j2;
    float acc = 0.f;
    const int k0 = kq * 64;
    #pragma unroll 8
    for (int k = 0; k < 64; ++k)
        acc += z[b * H + k0 + k] * Wl2h[(size_t)(k0 + k) * H + j];
    part[kq][j2][b] = acc;
    __syncthreads();
    if (t < 32) {
        float a = bl2h[j];
        #pragma unroll
        for (int q = 0; q < 8; ++q) a += part[q][j2][b];

        const int preh[3][3] = { { 1, 0, -1 },
                                 { 0, -1, 1 },
                                 { -1, 1, 0 } };
        #pragma unroll
        for (int l = 0; l < 3; ++l)
            #pragma unroll
            for (int p = 0; p < 3; ++p) {
                float v = (preh[l][p] < 0) ? stampf(a, 1u)
                                           : __uint_as_float((unsigned)preh[l][p]);
                ws[WS_STATE(l, p) + j * 16 + b] = v;
            }
        const unsigned preA1[3] = { 1u, 0u, 0u };
        #pragma unroll
        for (int p = 0; p < 3; ++p)
            ws[WS_A1(p) + j * 16 + b] = __uint_as_float(preA1[p]);
    }
}

// ---------------- persistent pipelined GRU + MLP decoder + streamed eij/argmax --
// 256 blocks, 1/CU by LDS (126 KB). Stage map (skew in parens):
//   job0 (0): bid   0..63,  8 cols, h@W_hh K-split over cs&1    -> STATE0
//   job1 (2): bid  64..127, 8 cols, phase A x@W_ih / B h@W_hh   -> STATE1
//   job2 (4): bid 128..191, 8 cols, phase A / B                 -> STATE2
//   job3 (5): bid 192..207, 32 cols, relu(h2@Wa1+ba1)           -> A1
//   job4 (6): bid 208..223, 32 cols, a1@Wa2+ba2                 -> atoms (stamped)
//   job5    : bid 224..255, persistent eij+argmax worker on the 32 spare CUs,
//             gated on job4 flags + atom stamps (write-once, no back-pressure).
// R6 core (proven 556us); R9 fence REVERTED (cost >> benefit; tau_vis is
// fabric-intrinsic — stores, atomics, and fences all measure the same).
__global__ __launch_bounds__(512, 2)
void k_gru(const float* __restrict__ W_ih, const float* __restrict__ W_hh,
           const float* __restrict__ b_ih, const float* __restrict__ b_hh,
           const float* __restrict__ Wa1,  const float* __restrict__ ba1,
           const float* __restrict__ Wa2,  const float* __restrict__ ba2,
           const float* __restrict__ Wb1,  const float* __restrict__ bb1,
           float* __restrict__ ws, float* __restrict__ out)
{
    __shared__ float sx[10240];
    __shared__ float sx2[10240];
    __shared__ float sh[10240];
    __shared__ float red[1536];
    unsigned* flags = (unsigned*)(ws + WS_E);

    const int bid = blockIdx.x;
    const int tid = threadIdx.x;

    int job, jbase;
    if      (bid < 64)  { job = 0; jbase = bid * 8; }
    else if (bid < 128) { job = 1; jbase = (bid - 64) * 8; }
    else if (bid < 192) { job = 2; jbase = (bid - 128) * 8; }
    else if (bid < 208) { job = 3; jbase = (bid - 192) * 32; }
    else if (bid < 224) { job = 4; jbase = (bid - 208) * 32; }
    else                { job = 5; jbase = 0; }

    // =================== job5: streamed eij + argmax worker ===================
    if (job == 5) {
        const int J = bid - 224;
        float* aT = sx;                        // 32 KB reuse
        // ---- eij tiles, timestep-ascending: i = t*16 + m*8 + ct ----
        for (int i = J; i < 1536; i += 32) {
            const int t = i >> 4, m = (i >> 3) & 1, ct = i & 7;
            // gate on job4 progress (cheap, sleep-backed; stamps are the truth)
            if (tid < 64) {
                unsigned lim = (unsigned)((t + 7 < 102) ? t + 7 : 102);
                for (;;) {
                    unsigned v = lim;
                    if (tid < 16) ld_coh_u32(&flags[208 + tid], v);
                    if (__all((int)(v >= lim))) break;
                    __builtin_amdgcn_s_sleep(32);
                }
            }
            __syncthreads();
            // stamp-verified transpose-stage of atoms[t*16..+16)[512]
            {
                const float* ap = ws + WS_ATOMS + (size_t)t * 16 * H;
                const int kq = tid & 127, b0r = tid >> 7;
                float4 va, vb, vc, vd;
                for (;;) {
                    ld_coh4(ap + (size_t)(b0r     ) * H + kq * 4,
                            ap + (size_t)(b0r + 4 ) * H + kq * 4,
                            ap + (size_t)(b0r + 8 ) * H + kq * 4,
                            ap + (size_t)(b0r + 12) * H + kq * 4,
                            va, vb, vc, vd);
                    if (__all(lsb4ok(va,1u) & lsb4ok(vb,1u) &
                              lsb4ok(vc,1u) & lsb4ok(vd,1u))) break;
                    __builtin_amdgcn_s_sleep(8);
                }
                aT[(kq*4+0)*16 + b0r     ] = va.x; aT[(kq*4+1)*16 + b0r     ] = va.y;
                aT[(kq*4+2)*16 + b0r     ] = va.z; aT[(kq*4+3)*16 + b0r     ] = va.w;
                aT[(kq*4+0)*16 + b0r + 4 ] = vb.x; aT[(kq*4+1)*16 + b0r + 4 ] = vb.y;
                aT[(kq*4+2)*16 + b0r + 4 ] = vb.z; aT[(kq*4+3)*16 + b0r + 4 ] = vb.w;
                aT[(kq*4+0)*16 + b0r + 8 ] = vc.x; aT[(kq*4+1)*16 + b0r + 8 ] = vc.y;
                aT[(kq*4+2)*16 + b0r + 8 ] = vc.z; aT[(kq*4+3)*16 + b0r + 8 ] = vc.w;
                aT[(kq*4+0)*16 + b0r + 12] = vd.x; aT[(kq*4+1)*16 + b0r + 12] = vd.y;
                aT[(kq*4+2)*16 + b0r + 12] = vd.z; aT[(kq*4+3)*16 + b0r + 12] = vd.w;
            }
            __syncthreads();
            // compute: 64 cols x 16 rows, 2 rows/thread
            {
                const int c = tid & 63, rg = tid >> 6;
                const int col = ct * 64 + c;
                const float* Wp = Wb1 + (size_t)m * H * H + col;
                float a0 = 0.f, a1 = 0.f;
                #pragma unroll 8
                for (int k = 0; k < 512; ++k) {
                    float wv = Wp[(size_t)k * H];
                    a0 += aT[k * 16 + rg * 2    ] * wv;
                    a1 += aT[k * 16 + rg * 2 + 1] * wv;
                }
                float bbv = (m == 0) ? bb1[col] : 0.f;
                float* eb = ws + WS_E + (size_t)(m * 16) * 96 * H;
                eb[((size_t)(rg * 2    ) * 96 + t) * H + col] = a0 + bbv;
                eb[((size_t)(rg * 2 + 1) * 96 + t) * H + col] = a1 + bbv;
            }
            __syncthreads();                   // aT reuse
        }
        // ---- argmax units (verified rows; first-max-wins) ----
        for (int u = J; u < 96; u += 32) {
            const int t = u;
            if (tid < 64) {
                unsigned lim = (unsigned)((t + 7 < 102) ? t + 7 : 102);
                for (;;) {
                    unsigned v = lim;
                    if (tid < 16) ld_coh_u32(&flags[208 + tid], v);
                    if (__all((int)(v >= lim))) break;
                    __builtin_amdgcn_s_sleep(32);
                }
            }
            __syncthreads();
            const int wv8 = tid >> 6, lane = tid & 63;
            for (int b = wv8; b < 16; b += 8) {
                const float* row = ws + WS_ATOMS + ((size_t)t * 16 + b) * H;
                float4 x0, x1;
                for (;;) {
                    ld_coh2(row + lane * 8, row + lane * 8 + 4, x0, x1);
                    if (__all(lsb4ok(x0, 1u) & lsb4ok(x1, 1u))) break;
                    __builtin_amdgcn_s_sleep(8);
                }
                float mx = x0.x; int mi = lane * 8;
                if (x0.y > mx) { mx = x0.y; mi = lane * 8 + 1; }
                if (x0.z > mx) { mx = x0.z; mi = lane * 8 + 2; }
                if (x0.w > mx) { mx = x0.w; mi = lane * 8 + 3; }
                if (x1.x > mx) { mx = x1.x; mi = lane * 8 + 4; }
                if (x1.y > mx) { mx = x1.y; mi = lane * 8 + 5; }
                if (x1.z > mx) { mx = x1.z; mi = lane * 8 + 6; }
                if (x1.w > mx) { mx = x1.w; mi = lane * 8 + 7; }
                #pragma unroll
                for (int off = 32; off >= 1; off >>= 1) {
                    float omx = __shfl_down(mx, off);
                    int   omi = __shfl_down(mi, off);
                    if (omx > mx || (omx == mx && omi < mi)) { mx = omx; mi = omi; }
                }
                if (lane == 0) out[b * 96 + t] = (float)mi;
            }
        }
        return;
    }

    // =================== jobs 0..4: R6 pipeline core ===================
    const int ks = tid & 31;
    const int cs = tid >> 6;

    // ---- anti-dep poll set: consumers of the buffer this stage writes ----
    int rs0, rc0;
    if      (job == 0) { rs0 = 0;   rc0 = 128; }
    else if (job == 1) { rs0 = 64;  rc0 = 128; }
    else if (job == 2) { rs0 = 128; rc0 = 80;  }
    else if (job == 3) { rs0 = 208; rc0 = 16;  }
    else               { rs0 = 0;   rc0 = 0;   }
    int fidl[2];
    #pragma unroll
    for (int e = 0; e < 2; ++e) {
        int idx = (tid & 63) + e * 64;
        fidl[e] = (idx < rc0) ? rs0 + idx : bid;   // own flag trivially passes
    }

    // ---- one-time weight preload into registers ----
    float w[6][16];
    if (job <= 2) {
        const int khalf = cs & 1, cpair = cs >> 1;
        const int colbase = jbase + cpair * 2;
        const float* WB = W_hh + (size_t)job * H * TH3;
        const float* WA = W_ih + (size_t)job * H * TH3;
        #pragma unroll
        for (int f = 0; f < 6; ++f) {
            int g = f >> 1, c = f & 1;
            #pragma unroll
            for (int kk = 0; kk < 8; ++kk) {
                size_t ro = (size_t)(khalf * 256 + kk * 32 + ks) * TH3 + g * 512 + colbase + c;
                w[f][8 + kk] = WB[ro];
                if (job != 0) w[f][kk] = WA[ro];
            }
        }
    } else {
        const float* base = (job == 3) ? Wa1 : Wa2;
        const int colbase = jbase + cs * 4;
        #pragma unroll
        for (int f = 0; f < 4; ++f)
            #pragma unroll
            for (int kk = 0; kk < 16; ++kk)
                w[f][kk] = base[(size_t)(kk * 32 + ks) * H + colbase + f];
    }

    // ---- epilogue constants (biases + running h for own cols) ----
    float c_bi0 = 0, c_bi1 = 0, c_bi2 = 0, c_bh0 = 0, c_bh1 = 0, c_bh2 = 0;
    float hp = 0.f, c_ba = 0.f;
    if (job <= 2) {
        if (tid < 128) {
            int b = tid & 15, j2 = tid >> 4, jc = jbase + j2;
            const float* bi  = b_ih + (size_t)job * TH3;
            const float* bhh = b_hh + (size_t)job * TH3;
            c_bi0 = bi[jc]; c_bi1 = bi[512 + jc]; c_bi2 = bi[1024 + jc];
            c_bh0 = bhh[jc]; c_bh1 = bhh[512 + jc]; c_bh2 = bhh[1024 + jc];
            const int hpp = (job == 0) ? 2 : (job == 1) ? 1 : 0;  // init-real parity
            hp = ws[WS_STATE(job, hpp) + jc * 16 + b];
        }
    } else if (job == 3) {
        c_ba = ba1[jbase + (tid >> 4)];
    } else {
        c_ba = ba2[jbase + (tid & 31)];
    }

    // ---- verify+stage one 32KB [512][16] buffer into LDS [512][20] (fused) ----
    auto stage32k = [&](const float* src, unsigned eb, float* dst) {
        const int k0 = tid >> 2, q4 = (tid & 3) * 4;
        float4 a, b, c, d;
        for (;;) {
            ld_coh4(src + 4 * tid, src + 4 * (tid + 512),
                    src + 4 * (tid + 1024), src + 4 * (tid + 1536), a, b, c, d);
            if (__all(lsb4ok(a, eb) & lsb4ok(b, eb) & lsb4ok(c, eb) & lsb4ok(d, eb)))
                break;
            __builtin_amdgcn_s_sleep(1);
        }
        *(float4*)&dst[(k0      ) * 20 + q4] = a;
        *(float4*)&dst[(k0 + 128) * 20 + q4] = b;
        *(float4*)&dst[(k0 + 256) * 20 + q4] = c;
        *(float4*)&dst[(k0 + 384) * 20 + q4] = d;
    };

    // ---- verify+stage TWO 32KB buffers in ONE round trip (jobs 1/2) ----
    auto stage64k = [&](const float* srcH, const float* srcX, unsigned eb,
                        float* dstH, float* dstX) {
        const int k0 = tid >> 2, q4 = (tid & 3) * 4;
        float4 xa, xb, xc, xd, ha, hb, hc, hd;
        for (;;) {
            ld_coh8(srcX + 4 * tid, srcX + 4 * (tid + 512),
                    srcX + 4 * (tid + 1024), srcX + 4 * (tid + 1536),
                    srcH + 4 * tid, srcH + 4 * (tid + 512),
                    srcH + 4 * (tid + 1024), srcH + 4 * (tid + 1536),
                    xa, xb, xc, xd, ha, hb, hc, hd);
            int ok = lsb4ok(xa, eb) & lsb4ok(xb, eb) & lsb4ok(xc, eb) & lsb4ok(xd, eb) &
                     lsb4ok(ha, eb) & lsb4ok(hb, eb) & lsb4ok(hc, eb) & lsb4ok(hd, eb);
            if (__all(ok)) break;
            __builtin_amdgcn_s_sleep(1);
        }
        *(float4*)&dstX[(k0      ) * 20 + q4] = xa;
        *(float4*)&dstX[(k0 + 128) * 20 + q4] = xb;
        *(float4*)&dstX[(k0 + 256) * 20 + q4] = xc;
        *(float4*)&dstX[(k0 + 384) * 20 + q4] = xd;
        *(float4*)&dstH[(k0      ) * 20 + q4] = ha;
        *(float4*)&dstH[(k0 + 128) * 20 + q4] = hb;
        *(float4*)&dstH[(k0 + 256) * 20 + q4] = hc;
        *(float4*)&dstH[(k0 + 384) * 20 + q4] = hd;
    };

    // ---- speculative flag check ----
    auto flagchk = [&](unsigned fv0, unsigned fv1, unsigned lim) {
        if (!__all((int)((fv0 >= lim) & (fv1 >= lim)))) {
            for (;;) {
                __builtin_amdgcn_s_sleep(1);
                unsigned v0, v1;
                ld_coh_u32x2(&flags[fidl[0]], &flags[fidl[1]], v0, v1);
                if (__all((int)((v0 >= lim) & (v1 >= lim)))) break;
            }
        }
    };

    // ---- K-split 6-gate matvec + reduce-scatter (jobs 0..2) ----
    auto mv6 = [&](const float* arr, int wo, int redbase) {
        const int qh = (tid >> 5) & 1;
        const int rowoff = 8 * qh;
        const bool b0 = (ks & 1), b1 = (ks & 2), b3 = (ks & 8), b4 = (ks & 16);
        const float* base = arr + (cs & 1) * (256 * 20);
        float acc[6][8];
        #pragma unroll
        for (int f = 0; f < 6; ++f)
            #pragma unroll
            for (int i = 0; i < 8; ++i) acc[f][i] = 0.f;
        #pragma unroll
        for (int kk = 0; kk < 8; ++kk) {
            const float* p = base + (kk * 32 + ks) * 20 + rowoff;
            float4 v0 = *(const float4*)p;
            float4 v1 = *(const float4*)(p + 4);
            #pragma unroll
            for (int f = 0; f < 6; ++f) {
                float wv = w[f][wo + kk];
                acc[f][0] += wv * v0.x; acc[f][1] += wv * v0.y;
                acc[f][2] += wv * v0.z; acc[f][3] += wv * v0.w;
                acc[f][4] += wv * v1.x; acc[f][5] += wv * v1.y;
                acc[f][6] += wv * v1.z; acc[f][7] += wv * v1.w;
            }
        }
        float a[6];
        #pragma unroll
        for (int f = 0; f < 6; ++f) {
            float t[4];
            #pragma unroll
            for (int j = 0; j < 4; ++j) {
                float give = b0 ? acc[f][j] : acc[f][j + 4];
                float recv = dppmov<DPP_XOR1>(give);
                float keep = b0 ? acc[f][j + 4] : acc[f][j];
                t[j] = keep + recv;
            }
            float u[2];
            #pragma unroll
            for (int j = 0; j < 2; ++j) {
                float give = b1 ? t[j] : t[j + 2];
                float recv = dppmov<DPP_XOR2>(give);
                float keep = b1 ? t[j + 2] : t[j];
                u[j] = keep + recv;
            }
            float give = b3 ? u[0] : u[1];
            float recv = dppmov<DPP_XOR8>(give);
            float keep = b3 ? u[1] : u[0];
            a[f] = keep + recv;
        }
        #pragma unroll
        for (int f = 0; f < 6; ++f) a[f] += swzf<SWZ_XOR4>(a[f]);
        float r[3];
        #pragma unroll
        for (int i = 0; i < 3; ++i) {
            float give = b4 ? a[i] : a[i + 3];
            float recv = swzf<SWZ_XOR16>(give);
            float keep = b4 ? a[i + 3] : a[i];
            r[i] = keep + recv;
        }
        if (!(ks & 4)) {
            int bl = ((ks & 1) << 2) | (ks & 2) | ((ks >> 3) & 1);
            int bb = ((tid >> 5) & 1) * 8 + bl;
            int fb3 = ((ks >> 4) & 1) * 3;
            #pragma unroll
            for (int i = 0; i < 3; ++i) {
                int f = fb3 + i, g = f >> 1, c = f & 1;
                red[redbase + (cs & 1) * 384 + g * 128 + ((cs >> 1) * 2 + c) * 16 + bb] = r[i];
            }
        }
    };

    // ---- 4-col matvec + reduce-scatter (jobs 3/4, 32 cols/block, 16 kk) ----
    auto mv4 = [&](const float* arr) {
        const int qh = (tid >> 5) & 1;
        const int rowoff = 8 * qh;
        const bool b0 = (ks & 1), b1 = (ks & 2), b3 = (ks & 8), b4 = (ks & 16);
        float acc[4][8];
        #pragma unroll
        for (int f = 0; f < 4; ++f)
            #pragma unroll
            for (int i = 0; i < 8; ++i) acc[f][i] = 0.f;
        #pragma unroll
        for (int kk = 0; kk < 16; ++kk) {
            const float* p = arr + (kk * 32 + ks) * 20 + rowoff;
            float4 v0 = *(const float4*)p;
            float4 v1 = *(const float4*)(p + 4);
            #pragma unroll
            for (int f = 0; f < 4; ++f) {
                float wv = w[f][kk];
                acc[f][0] += wv * v0.x; acc[f][1] += wv * v0.y;
                acc[f][2] += wv * v0.z; acc[f][3] += wv * v0.w;
                acc[f][4] += wv * v1.x; acc[f][5] += wv * v1.y;
                acc[f][6] += wv * v1.z; acc[f][7] += wv * v1.w;
            }
        }
        float a[4];
        #pragma unroll
        for (int f = 0; f < 4; ++f) {
            float t[4];
            #pragma unroll
            for (int j = 0; j < 4; ++j) {
                float give = b0 ? acc[f][j] : acc[f][j + 4];
                float recv = dppmov<DPP_XOR1>(give);
                float keep = b0 ? acc[f][j + 4] : acc[f][j];
                t[j] = keep + recv;
            }
            float u[2];
            #pragma unroll
            for (int j = 0; j < 2; ++j) {
                float give = b1 ? t[j] : t[j + 2];
                float recv = dppmov<DPP_XOR2>(give);
                float keep = b1 ? t[j + 2] : t[j];
                u[j] = keep + recv;
            }
            float give = b3 ? u[0] : u[1];
            float recv = dppmov<DPP_XOR8>(give);
            float keep = b3 ? u[1] : u[0];
            a[f] = keep + recv;
        }
        #pragma unroll
        for (int f = 0; f < 4; ++f) a[f] += swzf<SWZ_XOR4>(a[f]);
        float r[2];
        #pragma unroll
        for (int i = 0; i < 2; ++i) {
            float give = b4 ? a[i] : a[i + 2];
            float recv = swzf<SWZ_XOR16>(give);
            float keep = b4 ? a[i + 2] : a[i];
            r[i] = keep + recv;
        }
        if (!(ks & 4)) {
            int bl = ((ks & 1) << 2) | (ks & 2) | ((ks >> 3) & 1);
            int bb = ((tid >> 5) & 1) * 8 + bl;
            int f2 = ((ks >> 4) & 1) * 2;
            #pragma unroll
            for (int i = 0; i < 2; ++i)
                red[(cs * 4 + f2 + i) * 16 + bb] = r[i];
        }
    };

    for (int s = 0; s < 102; ++s) {
        const int rp = (s + 2) % 3, wp = s % 3;      // rp = (s-1)%3: 1-back parity
        const unsigned expb = (unsigned)((s + 1) & 1);
        const unsigned myb  = (unsigned)(s & 1);
        int act;
        if      (job == 0) act = (s <= 95);
        else if (job == 1) act = (s >= 2 && s <= 97);
        else if (job == 2) act = (s >= 4 && s <= 99);
        else if (job == 3) act = (s >= 5 && s <= 100);
        else               act = (s >= 6 && s <= 101);
        const int s0 = (job == 1) ? 2 : 4;
        const int dox = (job == 1 || job == 2) && (s >= s0 - 1) && (s <= s0 + 94);
        float* rbuf = (s & 1) ? sx2 : sx;            // x read at step s
        float* wbuf = (s & 1) ? sx : sx2;            // x staged for step s+1
        bool posted = false;

        if (act) {
            // ---- speculative anti-dep: issue 2 flag dwords, no wait ----
            unsigned fv0 = 0xFFFFFFFFu, fv1 = 0xFFFFFFFFu;
            const bool needchk = (tid < 64) && (s >= 2);
            if (needchk)
                ld_coh_u32x2_issue(&flags[fidl[0]], &flags[fidl[1]], fv0, fv1);

            if (job == 1 || job == 2) {
                const float* srcH = ws + WS_STATE(job, rp);
                const float* srcX = ws + WS_STATE(job - 1, rp);
                mv6(rbuf, 0, 0);
                if (dox)
                    stage64k(srcH, srcX, expb, sh, wbuf);
                else
                    stage32k(srcH, expb, sh);
                if (needchk) { vm_wait0(); flagchk(fv0, fv1, (unsigned)(s - 1)); }
                __syncthreads();
                if (tid == 0) st_coh_u32(&flags[bid], (unsigned)(s + 1));
                posted = true;
                mv6(sh, 8, 768);
                __syncthreads();
                if (tid < 128) {
                    int b = tid & 15, jc = jbase + (tid >> 4);
                    int o = tid;
                    float gi0 = red[o]        + red[384 + o];
                    float gi1 = red[128 + o]  + red[512 + o];
                    float gi2 = red[256 + o]  + red[640 + o];
                    float gh0 = red[768 + o]  + red[1152 + o];
                    float gh1 = red[896 + o]  + red[1280 + o];
                    float gh2 = red[1024 + o] + red[1408 + o];
                    float r  = sigm_(gi0 + c_bi0 + gh0 + c_bh0);
                    float zg = sigm_(gi1 + c_bi1 + gh1 + c_bh1);
                    float n  = tanhf(gi2 + c_bi2 + r * (gh2 + c_bh2));
                    float hn = (1.f - zg) * n + zg * hp;
                    hp = hn;
                    st_coh1(&ws[WS_STATE(job, wp) + jc * 16 + b], stampf(hn, myb));
                }
            } else if (job == 0) {
                stage32k(ws + WS_STATE(0, rp), expb, sx);
                if (needchk) { vm_wait0(); flagchk(fv0, fv1, (unsigned)(s - 1)); }
                __syncthreads();
                if (tid == 0) st_coh_u32(&flags[bid], (unsigned)(s + 1));
                posted = true;
                mv6(sx, 8, 768);
                __syncthreads();
                if (tid < 128) {
                    int b = tid & 15, jc = jbase + (tid >> 4);
                    int o = tid;
                    float g0 = red[768 + o]  + red[1152 + o];
                    float g1 = red[896 + o]  + red[1280 + o];
                    float g2 = red[1024 + o] + red[1408 + o];
                    float r  = sigm_(c_bi0 + g0 + c_bh0);
                    float zg = sigm_(c_bi1 + g1 + c_bh1);
                    float n  = tanhf(c_bi2 + r * (g2 + c_bh2));
                    float hn = (1.f - zg) * n + zg * hp;
                    hp = hn;
                    st_coh1(&ws[WS_STATE(0, wp) + jc * 16 + b], stampf(hn, myb));
                }
            } else {
                const float* srcp = (job == 3) ? (ws + WS_STATE(2, rp))
                                               : (ws + WS_A1(rp));
                stage32k(srcp, expb, sx);
                if (needchk) { vm_wait0(); flagchk(fv0, fv1, (unsigned)(s - 1)); }
                __syncthreads();
                if (tid == 0) st_coh_u32(&flags[bid], (unsigned)(s + 1));
                posted = true;
                mv4(sx);
                __syncthreads();
                if (job == 3) {
                    int b = tid & 15, j2 = tid >> 4, jc = jbase + j2;
                    float v = red[j2 * 16 + b] + c_ba;
                    st_coh1(&ws[WS_A1(wp) + jc * 16 + b], stampf(fmaxf(v, 0.f), myb));
                } else {
                    // job4: publish atoms with stamp LSB=1 (consumed by job5)
                    int j2 = tid & 31, b = tid >> 5, jc = jbase + j2;
                    float v = red[j2 * 16 + b] + c_ba;
                    st_coh1(&ws[WS_ATOMS + ((size_t)(s - 6) * 16 + b) * H + jc],
                            stampf(v, 1u));
                }
            }
        } else if (dox) {
            stage32k(ws + WS_STATE(job - 1, rp), expb, wbuf);
        }

        __syncthreads();
        if (!posted && tid == 0) st_coh_u32(&flags[bid], (unsigned)(s + 1));
    }
}

// ---------------- fused edge MLP: relu(e_i + e_j) @ Wb2 + bb2, diag zeroed ----
extern "C" __global__ __launch_bounds__(256)
void k_edge(const float* __restrict__ Wb2, const float* __restrict__ bb2,
            const float* __restrict__ ws, float* __restrict__ out)
{
    __shared__ float ls[32][260];
    __shared__ float wsm[2048];
    const int bid = blockIdx.x;                // b*36 + it*6 + jt
    const int b = bid / 36, r6 = bid % 36, it = r6 / 6, jt = r6 % 6;
    const int tid = threadIdx.x;
    const int ip = tid & 15, jp = tid >> 4;
    float acc0 = 0, acc1 = 0, acc2 = 0, acc3 = 0;

    for (int f = tid; f < 2048; f += 256)      // Wb2 -> LDS (one-time)
        wsm[f] = Wb2[f];

    for (int ph = 0; ph < 2; ++ph) {
        __syncthreads();
        for (int f = tid; f < 2048; f += 256) {
            int r = f >> 6, c4 = f & 63;
            const float* src = (r < 16)
                ? ws + WS_E + ((size_t)b * 96 + it * 16 + r) * H
                : ws + WS_E + ((size_t)(16 + b) * 96 + jt * 16 + (r - 16)) * H;
            float4 v = *(const float4*)(src + ph * 256 + c4 * 4);
            *(float4*)&ls[r][c4 * 4] = v;
        }
        __syncthreads();
        const float* wb = &wsm[ph * 1024];
        #pragma unroll 2
        for (int hh = 0; hh < 256; hh += 4) {
            float4 ei = *(const float4*)&ls[ip][hh];
            float4 ej = *(const float4*)&ls[16 + jp][hh];
            float4 w0 = *(const float4*)(wb + (size_t)hh * 4);
            float4 w1 = *(const float4*)(wb + (size_t)hh * 4 + 4);
            float4 w2 = *(const float4*)(wb + (size_t)hh * 4 + 8);
            float4 w3 = *(const float4*)(wb + (size_t)hh * 4 + 12);
            float v;
            v = fmaxf(ei.x + ej.x, 0.f); acc0 += v * w0.x; acc1 += v * w0.y; acc2 += v * w0.z; acc3 += v * w0.w;
            v = fmaxf(ei.y + ej.y, 0.f); acc0 += v * w1.x; acc1 += v * w1.y; acc2 += v * w1.z; acc3 += v * w1.w;
            v = fmaxf(ei.z + ej.z, 0.f); acc0 += v * w2.x; acc1 += v * w2.y; acc2 += v * w2.z; acc3 += v * w2.w;
            v = fmaxf(ei.w + ej.w, 0.f); acc0 += v * w3.x; acc1 += v * w3.y; acc2 += v * w3.z; acc3 += v * w3.w;
        }
    }
    const int i = it * 16 + ip, j = jt * 16 + jp;
    float4 o;
    if (i == j) { o.x = 0.f; o.y = 0.f; o.z = 0.f; o.w = 0.f; }
    else { o.x = acc0 + bb2[0]; o.y = acc1 + bb2[1]; o.z = acc2 + bb2[2]; o.w = acc3 + bb2[3]; }
    *(float4*)(out + 1536 + (((size_t)b * 96 + i) * 96 + j) * 4) = o;
}

// ---------------- host ----------------
extern "C" void kernel_launch(void* const* d_in, const int* in_sizes, int n_in,
                              void* d_out, int out_size, void* d_ws, size_t ws_size,
                              hipStream_t stream)
{
    const float* z    = (const float*)d_in[0];
    const float* Wl2h = (const float*)d_in[1];
    const float* bl2h = (const float*)d_in[2];
    const float* W_ih = (const float*)d_in[3];
    const float* W_hh = (const float*)d_in[4];
    const float* b_ih = (const float*)d_in[5];
    const float* b_hh = (const float*)d_in[6];
    const float* Wa1  = (const float*)d_in[7];
    const float* ba1  = (const float*)d_in[8];
    const float* Wa2  = (const float*)d_in[9];
    const float* ba2  = (const float*)d_in[10];
    const float* Wb1  = (const float*)d_in[11];
    const float* bb1  = (const float*)d_in[12];
    const float* Wb2  = (const float*)d_in[13];
    const float* bb2  = (const float*)d_in[14];
    float* out = (float*)d_out;
    float* ws  = (float*)d_ws;

    hipLaunchKernelGGL(k_init, dim3(256), dim3(256), 0, stream, z, Wl2h, bl2h, ws);

    // grid 256 = 224 pipeline blocks + 32 streamed eij/argmax workers;
    // 1 block/CU by LDS -> all co-resident, core blocks dispatched first.
    hipLaunchKernelGGL(k_gru, dim3(GRID), dim3(512), 0, stream,
                       W_ih, W_hh, b_ih, b_hh, Wa1, ba1, Wa2, ba2,
                       Wb1, bb1, ws, out);

    hipLaunchKernelGGL(k_edge, dim3(576), dim3(256), 0, stream, Wb2, bb2, ws, out);
}

// Round 11
// 944.228 us; speedup vs baseline: 1.3060x; 1.0665x over previous
//
#include <hip/hip_runtime.h>
#include <math.h>

#define H    512
#define TH3  1536
#define GRID 256

// ---------------- workspace layout (float offsets), P=3 parities ----------------
#define WS_STATE(l,p) ((size_t)((l)*3+(p)) * 8192)          // 0 .. 73728
#define WS_A1(p)      ((size_t)73728 + (size_t)(p)*8192)    // 73728 .. 98304
#define WS_ATOMS      ((size_t)98304)                        // 98304 .. 884736
#define WS_E          ((size_t)884736)                       // e_i/e_j buffers
// flags u32[256] at WS_E during k_gru. NOTE: e_i[b=0][t=0][col<256] aliases the
// flags — job5 DEFERS those 256 words until all core flags read 102 (final).

__device__ __forceinline__ float sigm_(float x) { return 1.0f / (1.0f + expf(-x)); }

// ---- LSB stamping: freshness tag lives in the data mantissa LSB ----
__device__ __forceinline__ float stampf(float x, unsigned b) {
    return __uint_as_float((__float_as_uint(x) & ~1u) | b);
}
__device__ __forceinline__ int lsb4ok(float4 v, unsigned e) {
    return ((__float_as_uint(v.x) & 1u) == e) & ((__float_as_uint(v.y) & 1u) == e) &
           ((__float_as_uint(v.z) & 1u) == e) & ((__float_as_uint(v.w) & 1u) == e);
}

// ---- coherent memory helpers (sc0 sc1) ----
__device__ __forceinline__ void ld_coh2(const float* p0, const float* p1,
                                        float4& a, float4& b)
{
    asm volatile(
        "global_load_dwordx4 %0, %2, off sc0 sc1\n\t"
        "global_load_dwordx4 %1, %3, off sc0 sc1\n\t"
        "s_waitcnt vmcnt(0)"
        : "=&v"(a), "=&v"(b)
        : "v"(p0), "v"(p1)
        : "memory");
}

__device__ __forceinline__ void ld_coh4(const float* p0, const float* p1,
                                        const float* p2, const float* p3,
                                        float4& a, float4& b, float4& c, float4& d)
{
    asm volatile(
        "global_load_dwordx4 %0, %4, off sc0 sc1\n\t"
        "global_load_dwordx4 %1, %5, off sc0 sc1\n\t"
        "global_load_dwordx4 %2, %6, off sc0 sc1\n\t"
        "global_load_dwordx4 %3, %7, off sc0 sc1\n\t"
        "s_waitcnt vmcnt(0)"
        : "=&v"(a), "=&v"(b), "=&v"(c), "=&v"(d)
        : "v"(p0), "v"(p1), "v"(p2), "v"(p3)
        : "memory");
}

__device__ __forceinline__ void ld_coh8(const float* p0, const float* p1,
                                        const float* p2, const float* p3,
                                        const float* p4, const float* p5,
                                        const float* p6, const float* p7,
                                        float4& a, float4& b, float4& c, float4& d,
                                        float4& e, float4& f, float4& g, float4& h)
{
    asm volatile(
        "global_load_dwordx4 %0, %8, off sc0 sc1\n\t"
        "global_load_dwordx4 %1, %9, off sc0 sc1\n\t"
        "global_load_dwordx4 %2, %10, off sc0 sc1\n\t"
        "global_load_dwordx4 %3, %11, off sc0 sc1\n\t"
        "global_load_dwordx4 %4, %12, off sc0 sc1\n\t"
        "global_load_dwordx4 %5, %13, off sc0 sc1\n\t"
        "global_load_dwordx4 %6, %14, off sc0 sc1\n\t"
        "global_load_dwordx4 %7, %15, off sc0 sc1\n\t"
        "s_waitcnt vmcnt(0)"
        : "=&v"(a), "=&v"(b), "=&v"(c), "=&v"(d),
          "=&v"(e), "=&v"(f), "=&v"(g), "=&v"(h)
        : "v"(p0), "v"(p1), "v"(p2), "v"(p3),
          "v"(p4), "v"(p5), "v"(p6), "v"(p7)
        : "memory");
}

// waitcnt + sched_barrier (rule-#18): pins subsequent register-only consumers
// below the wait; no tied operands (gfx950 rejects tied 128-bit inline asm).
__device__ __forceinline__ void vm_wait0() {
    asm volatile("s_waitcnt vmcnt(0)" ::: "memory");
    __builtin_amdgcn_sched_barrier(0);
}

__device__ __forceinline__ void st_coh1(float* p, float v) {
    asm volatile("global_store_dword %0, %1, off sc0 sc1" :: "v"(p), "v"(v) : "memory");
}

__device__ __forceinline__ void ld_coh_u32(const unsigned* p, unsigned& a) {
    asm volatile(
        "global_load_dword %0, %1, off sc0 sc1\n\t"
        "s_waitcnt vmcnt(0)"
        : "=&v"(a) : "v"(p) : "memory");
}

__device__ __forceinline__ void ld_coh_u32x2(const unsigned* p0, const unsigned* p1,
                                             unsigned& a, unsigned& b)
{
    asm volatile(
        "global_load_dword %0, %2, off sc0 sc1\n\t"
        "global_load_dword %1, %3, off sc0 sc1\n\t"
        "s_waitcnt vmcnt(0)"
        : "=&v"(a), "=&v"(b)
        : "v"(p0), "v"(p1)
        : "memory");
}

// issue-only flag loads: fly across the stage; its vmcnt(0) drains them.
__device__ __forceinline__ void ld_coh_u32x2_issue(const unsigned* p0, const unsigned* p1,
                                                   unsigned& a, unsigned& b)
{
    asm volatile(
        "global_load_dword %0, %2, off sc0 sc1\n\t"
        "global_load_dword %1, %3, off sc0 sc1"
        : "=&v"(a), "=&v"(b)
        : "v"(p0), "v"(p1)
        : "memory");
}

__device__ __forceinline__ void st_coh_u32(unsigned* p, unsigned v) {
    asm volatile("global_store_dword %0, %1, off sc0 sc1" :: "v"(p), "v"(v) : "memory");
}

// ---- cross-lane helpers: DPP (VALU) for xor1/xor2/xor8, ds_swizzle for xor4/xor16 ----
template<int CTRL>
__device__ __forceinline__ float dppmov(float v) {
    return __int_as_float(__builtin_amdgcn_update_dpp(
        0, __float_as_int(v), CTRL, 0xF, 0xF, true));
}
#define DPP_XOR1 0xB1   // quad_perm(1,0,3,2)
#define DPP_XOR2 0x4E   // quad_perm(2,3,0,1)
#define DPP_XOR8 0x128  // row_ror:8  (== xor8 within 16)

template<int PAT>
__device__ __forceinline__ float swzf(float v) {
    return __int_as_float(__builtin_amdgcn_ds_swizzle(__float_as_int(v), PAT));
}
#define SWZ_XOR4  0x101F
#define SWZ_XOR16 0x401F

// ---------------- h_init: z @ W_l2h + b_l2h, LSB-stamped parities ----------------
// 256 blocks, 8-way K-split + LDS reduce. Also zeroes the atoms region so its
// stamp LSBs read 0 until job4 publishes stamped (LSB=1) values.
extern "C" __global__ __launch_bounds__(256)
void k_init(const float* __restrict__ z, const float* __restrict__ Wl2h,
            const float* __restrict__ bl2h, float* __restrict__ ws)
{
    __shared__ float part[8][2][16];
    if (blockIdx.x == 0)
        ((unsigned*)(ws + WS_E))[threadIdx.x] = 0u;   // flags[0..255]
    const int t  = threadIdx.x;

    // zero atoms stamps: 786432 floats == 65536 threads x 12
    {
        float4 z4 = make_float4(0.f, 0.f, 0.f, 0.f);
        size_t base = WS_ATOMS + ((size_t)blockIdx.x * 256 + t) * 12;
        #pragma unroll
        for (int q = 0; q < 3; ++q)
            *(float4*)&ws[base + q * 4] = z4;
    }

    const int b  = t & 15, j2 = (t >> 4) & 1, kq = t >> 5;   // kq 0..7
    const int j  = blockIdx.x * 2 + j2;
    float acc = 0.f;
    const int k0 = kq * 64;
    #pragma unroll 8
    for (int k = 0; k < 64; ++k)
        acc += z[b * H + k0 + k] * Wl2h[(size_t)(k0 + k) * H + j];
    part[kq][j2][b] = acc;
    __syncthreads();
    if (t < 32) {
        float a = bl2h[j];
        #pragma unroll
        for (int q = 0; q < 8; ++q) a += part[q][j2][b];

        const int preh[3][3] = { { 1, 0, -1 },
                                 { 0, -1, 1 },
                                 { -1, 1, 0 } };
        #pragma unroll
        for (int l = 0; l < 3; ++l)
            #pragma unroll
            for (int p = 0; p < 3; ++p) {
                float v = (preh[l][p] < 0) ? stampf(a, 1u)
                                           : __uint_as_float((unsigned)preh[l][p]);
                ws[WS_STATE(l, p) + j * 16 + b] = v;
            }
        const unsigned preA1[3] = { 1u, 0u, 0u };
        #pragma unroll
        for (int p = 0; p < 3; ++p)
            ws[WS_A1(p) + j * 16 + b] = __uint_as_float(preA1[p]);
    }
}

// ---------------- persistent pipelined GRU + MLP decoder + streamed eij/argmax --
// 256 blocks, 1/CU by LDS (126 KB). Stage map (skew in parens):
//   job0 (0): bid   0..63,  8 cols, h@W_hh K-split over cs&1    -> STATE0
//   job1 (2): bid  64..127, 8 cols, phase A x@W_ih / B h@W_hh   -> STATE1
//   job2 (4): bid 128..191, 8 cols, phase A / B                 -> STATE2
//   job3 (5): bid 192..207, 32 cols, relu(h2@Wa1+ba1)           -> A1
//   job4 (6): bid 208..223, 32 cols, a1@Wa2+ba2                 -> atoms (stamped)
//   job5    : bid 224..255, streamed eij+argmax on 32 spare CUs.
// R10 fixes: (1) e_i[0][0][0..255] aliases flags -> DEFERRED until all core
// flags == 102 (safe: a core block's final post follows its last poll);
// (2) gate at t+8 (job4 posts flag BEFORE its epilogue writes atoms);
// (3) aT stride 16 -> 20 (32-way -> 2-way LDS bank conflict).
__global__ __launch_bounds__(512, 2)
void k_gru(const float* __restrict__ W_ih, const float* __restrict__ W_hh,
           const float* __restrict__ b_ih, const float* __restrict__ b_hh,
           const float* __restrict__ Wa1,  const float* __restrict__ ba1,
           const float* __restrict__ Wa2,  const float* __restrict__ ba2,
           const float* __restrict__ Wb1,  const float* __restrict__ bb1,
           float* __restrict__ ws, float* __restrict__ out)
{
    __shared__ float sx[10240];
    __shared__ float sx2[10240];
    __shared__ float sh[10240];
    __shared__ float red[1536];
    unsigned* flags = (unsigned*)(ws + WS_E);

    const int bid = blockIdx.x;
    const int tid = threadIdx.x;

    int job, jbase;
    if      (bid < 64)  { job = 0; jbase = bid * 8; }
    else if (bid < 128) { job = 1; jbase = (bid - 64) * 8; }
    else if (bid < 192) { job = 2; jbase = (bid - 128) * 8; }
    else if (bid < 208) { job = 3; jbase = (bid - 192) * 32; }
    else if (bid < 224) { job = 4; jbase = (bid - 208) * 32; }
    else                { job = 5; jbase = 0; }

    // =================== job5: streamed eij + argmax worker ===================
    if (job == 5) {
        const int J = bid - 224;
        float* aT = sx;                        // [512][20], 40960B reuse of sx
        float defer = 0.f; int hasdef = 0;
        // ---- eij tiles, timestep-ascending: i = t*16 + m*8 + ct ----
        for (int i = J; i < 1536; i += 32) {
            const int t = i >> 4, m = (i >> 3) & 1, ct = i & 7;
            // gate on job4 progress: flag t+8 means step t+7's FIRST barrier
            // passed, which follows step t+6's epilogue (the atoms write for t).
            if (tid < 64) {
                unsigned lim = (unsigned)((t + 8 < 102) ? t + 8 : 102);
                for (;;) {
                    unsigned v = lim;
                    if (tid < 16) ld_coh_u32(&flags[208 + tid], v);
                    if (__all((int)(v >= lim))) break;
                    __builtin_amdgcn_s_sleep(32);
                }
            }
            __syncthreads();
            // stamp-verified transpose-stage of atoms[t*16..+16)[512]
            {
                const float* ap = ws + WS_ATOMS + (size_t)t * 16 * H;
                const int kq = tid & 127, b0r = tid >> 7;
                float4 va, vb, vc, vd;
                for (;;) {
                    ld_coh4(ap + (size_t)(b0r     ) * H + kq * 4,
                            ap + (size_t)(b0r + 4 ) * H + kq * 4,
                            ap + (size_t)(b0r + 8 ) * H + kq * 4,
                            ap + (size_t)(b0r + 12) * H + kq * 4,
                            va, vb, vc, vd);
                    if (__all(lsb4ok(va,1u) & lsb4ok(vb,1u) &
                              lsb4ok(vc,1u) & lsb4ok(vd,1u))) break;
                    __builtin_amdgcn_s_sleep(8);
                }
                aT[(kq*4+0)*20 + b0r     ] = va.x; aT[(kq*4+1)*20 + b0r     ] = va.y;
                aT[(kq*4+2)*20 + b0r     ] = va.z; aT[(kq*4+3)*20 + b0r     ] = va.w;
                aT[(kq*4+0)*20 + b0r + 4 ] = vb.x; aT[(kq*4+1)*20 + b0r + 4 ] = vb.y;
                aT[(kq*4+2)*20 + b0r + 4 ] = vb.z; aT[(kq*4+3)*20 + b0r + 4 ] = vb.w;
                aT[(kq*4+0)*20 + b0r + 8 ] = vc.x; aT[(kq*4+1)*20 + b0r + 8 ] = vc.y;
                aT[(kq*4+2)*20 + b0r + 8 ] = vc.z; aT[(kq*4+3)*20 + b0r + 8 ] = vc.w;
                aT[(kq*4+0)*20 + b0r + 12] = vd.x; aT[(kq*4+1)*20 + b0r + 12] = vd.y;
                aT[(kq*4+2)*20 + b0r + 12] = vd.z; aT[(kq*4+3)*20 + b0r + 12] = vd.w;
            }
            __syncthreads();
            // compute: 64 cols x 16 rows, 2 rows/thread
            {
                const int c = tid & 63, rg = tid >> 6;
                const int col = ct * 64 + c;
                const float* Wp = Wb1 + (size_t)m * H * H + col;
                float a0 = 0.f, a1 = 0.f;
                #pragma unroll 8
                for (int k = 0; k < 512; ++k) {
                    float wv = Wp[(size_t)k * H];
                    a0 += aT[k * 20 + rg * 2    ] * wv;
                    a1 += aT[k * 20 + rg * 2 + 1] * wv;
                }
                float bbv = (m == 0) ? bb1[col] : 0.f;
                float* eb = ws + WS_E + (size_t)(m * 16) * 96 * H;
                if (i < 4 && rg == 0) {        // e_i[0][0][col<256]: aliases flags
                    defer = a0 + bbv; hasdef = 1;
                } else {
                    eb[((size_t)(rg * 2) * 96 + t) * H + col] = a0 + bbv;
                }
                eb[((size_t)(rg * 2 + 1) * 96 + t) * H + col] = a1 + bbv;
            }
            __syncthreads();                   // aT reuse
        }
        // ---- argmax units (stamp-verified rows; first-max-wins) ----
        for (int u = J; u < 96; u += 32) {
            const int t = u;
            if (tid < 64) {
                unsigned lim = (unsigned)((t + 8 < 102) ? t + 8 : 102);
                for (;;) {
                    unsigned v = lim;
                    if (tid < 16) ld_coh_u32(&flags[208 + tid], v);
                    if (__all((int)(v >= lim))) break;
                    __builtin_amdgcn_s_sleep(32);
                }
            }
            __syncthreads();
            const int wv8 = tid >> 6, lane = tid & 63;
            for (int b = wv8; b < 16; b += 8) {
                const float* row = ws + WS_ATOMS + ((size_t)t * 16 + b) * H;
                float4 x0, x1;
                for (;;) {
                    ld_coh2(row + lane * 8, row + lane * 8 + 4, x0, x1);
                    if (__all(lsb4ok(x0, 1u) & lsb4ok(x1, 1u))) break;
                    __builtin_amdgcn_s_sleep(8);
                }
                float mx = x0.x; int mi = lane * 8;
                if (x0.y > mx) { mx = x0.y; mi = lane * 8 + 1; }
                if (x0.z > mx) { mx = x0.z; mi = lane * 8 + 2; }
                if (x0.w > mx) { mx = x0.w; mi = lane * 8 + 3; }
                if (x1.x > mx) { mx = x1.x; mi = lane * 8 + 4; }
                if (x1.y > mx) { mx = x1.y; mi = lane * 8 + 5; }
                if (x1.z > mx) { mx = x1.z; mi = lane * 8 + 6; }
                if (x1.w > mx) { mx = x1.w; mi = lane * 8 + 7; }
                #pragma unroll
                for (int off = 32; off >= 1; off >>= 1) {
                    float omx = __shfl_down(mx, off);
                    int   omi = __shfl_down(mi, off);
                    if (omx > mx || (omx == mx && omi < mi)) { mx = omx; mi = omi; }
                }
                if (lane == 0) out[b * 96 + t] = (float)mi;
            }
        }
        // ---- deferred flush: wait until every core flag reads 102 (final).
        // A core block's final post (102) follows its last poll, so once all
        // flags[0..223] == 102 no block will ever poll again -> safe to write.
        if (J < 4 && tid < 64 && hasdef) {
            for (;;) {
                unsigned v0, v1, v2, v3;
                ld_coh_u32x2(&flags[tid], &flags[tid + 64], v0, v1);
                ld_coh_u32x2(&flags[tid + 128], &flags[192 + (tid & 31)], v2, v3);
                if (__all((int)((v0 >= 102u) & (v1 >= 102u) &
                                (v2 >= 102u) & (v3 >= 102u)))) break;
                __builtin_amdgcn_s_sleep(32);
            }
            st_coh1(&ws[WS_E + (size_t)J * 64 + tid], defer);
        }
        return;
    }

    // =================== jobs 0..4: R6 pipeline core ===================
    const int ks = tid & 31;
    const int cs = tid >> 6;

    // ---- anti-dep poll set: consumers of the buffer this stage writes ----
    int rs0, rc0;
    if      (job == 0) { rs0 = 0;   rc0 = 128; }
    else if (job == 1) { rs0 = 64;  rc0 = 128; }
    else if (job == 2) { rs0 = 128; rc0 = 80;  }
    else if (job == 3) { rs0 = 208; rc0 = 16;  }
    else               { rs0 = 0;   rc0 = 0;   }
    int fidl[2];
    #pragma unroll
    for (int e = 0; e < 2; ++e) {
        int idx = (tid & 63) + e * 64;
        fidl[e] = (idx < rc0) ? rs0 + idx : bid;   // own flag trivially passes
    }

    // ---- one-time weight preload into registers ----
    float w[6][16];
    if (job <= 2) {
        const int khalf = cs & 1, cpair = cs >> 1;
        const int colbase = jbase + cpair * 2;
        const float* WB = W_hh + (size_t)job * H * TH3;
        const float* WA = W_ih + (size_t)job * H * TH3;
        #pragma unroll
        for (int f = 0; f < 6; ++f) {
            int g = f >> 1, c = f & 1;
            #pragma unroll
            for (int kk = 0; kk < 8; ++kk) {
                size_t ro = (size_t)(khalf * 256 + kk * 32 + ks) * TH3 + g * 512 + colbase + c;
                w[f][8 + kk] = WB[ro];
                if (job != 0) w[f][kk] = WA[ro];
            }
        }
    } else {
        const float* base = (job == 3) ? Wa1 : Wa2;
        const int colbase = jbase + cs * 4;
        #pragma unroll
        for (int f = 0; f < 4; ++f)
            #pragma unroll
            for (int kk = 0; kk < 16; ++kk)
                w[f][kk] = base[(size_t)(kk * 32 + ks) * H + colbase + f];
    }

    // ---- epilogue constants (biases + running h for own cols) ----
    float c_bi0 = 0, c_bi1 = 0, c_bi2 = 0, c_bh0 = 0, c_bh1 = 0, c_bh2 = 0;
    float hp = 0.f, c_ba = 0.f;
    if (job <= 2) {
        if (tid < 128) {
            int b = tid & 15, j2 = tid >> 4, jc = jbase + j2;
            const float* bi  = b_ih + (size_t)job * TH3;
            const float* bhh = b_hh + (size_t)job * TH3;
            c_bi0 = bi[jc]; c_bi1 = bi[512 + jc]; c_bi2 = bi[1024 + jc];
            c_bh0 = bhh[jc]; c_bh1 = bhh[512 + jc]; c_bh2 = bhh[1024 + jc];
            const int hpp = (job == 0) ? 2 : (job == 1) ? 1 : 0;  // init-real parity
            hp = ws[WS_STATE(job, hpp) + jc * 16 + b];
        }
    } else if (job == 3) {
        c_ba = ba1[jbase + (tid >> 4)];
    } else {
        c_ba = ba2[jbase + (tid & 31)];
    }

    // ---- verify+stage one 32KB [512][16] buffer into LDS [512][20] (fused) ----
    auto stage32k = [&](const float* src, unsigned eb, float* dst) {
        const int k0 = tid >> 2, q4 = (tid & 3) * 4;
        float4 a, b, c, d;
        for (;;) {
            ld_coh4(src + 4 * tid, src + 4 * (tid + 512),
                    src + 4 * (tid + 1024), src + 4 * (tid + 1536), a, b, c, d);
            if (__all(lsb4ok(a, eb) & lsb4ok(b, eb) & lsb4ok(c, eb) & lsb4ok(d, eb)))
                break;
            __builtin_amdgcn_s_sleep(1);
        }
        *(float4*)&dst[(k0      ) * 20 + q4] = a;
        *(float4*)&dst[(k0 + 128) * 20 + q4] = b;
        *(float4*)&dst[(k0 + 256) * 20 + q4] = c;
        *(float4*)&dst[(k0 + 384) * 20 + q4] = d;
    };

    // ---- verify+stage TWO 32KB buffers in ONE round trip (jobs 1/2) ----
    auto stage64k = [&](const float* srcH, const float* srcX, unsigned eb,
                        float* dstH, float* dstX) {
        const int k0 = tid >> 2, q4 = (tid & 3) * 4;
        float4 xa, xb, xc, xd, ha, hb, hc, hd;
        for (;;) {
            ld_coh8(srcX + 4 * tid, srcX + 4 * (tid + 512),
                    srcX + 4 * (tid + 1024), srcX + 4 * (tid + 1536),
                    srcH + 4 * tid, srcH + 4 * (tid + 512),
                    srcH + 4 * (tid + 1024), srcH + 4 * (tid + 1536),
                    xa, xb, xc, xd, ha, hb, hc, hd);
            int ok = lsb4ok(xa, eb) & lsb4ok(xb, eb) & lsb4ok(xc, eb) & lsb4ok(xd, eb) &
                     lsb4ok(ha, eb) & lsb4ok(hb, eb) & lsb4ok(hc, eb) & lsb4ok(hd, eb);
            if (__all(ok)) break;
            __builtin_amdgcn_s_sleep(1);
        }
        *(float4*)&dstX[(k0      ) * 20 + q4] = xa;
        *(float4*)&dstX[(k0 + 128) * 20 + q4] = xb;
        *(float4*)&dstX[(k0 + 256) * 20 + q4] = xc;
        *(float4*)&dstX[(k0 + 384) * 20 + q4] = xd;
        *(float4*)&dstH[(k0      ) * 20 + q4] = ha;
        *(float4*)&dstH[(k0 + 128) * 20 + q4] = hb;
        *(float4*)&dstH[(k0 + 256) * 20 + q4] = hc;
        *(float4*)&dstH[(k0 + 384) * 20 + q4] = hd;
    };

    // ---- speculative flag check ----
    auto flagchk = [&](unsigned fv0, unsigned fv1, unsigned lim) {
        if (!__all((int)((fv0 >= lim) & (fv1 >= lim)))) {
            for (;;) {
                __builtin_amdgcn_s_sleep(1);
                unsigned v0, v1;
                ld_coh_u32x2(&flags[fidl[0]], &flags[fidl[1]], v0, v1);
                if (__all((int)((v0 >= lim) & (v1 >= lim)))) break;
            }
        }
    };

    // ---- K-split 6-gate matvec + reduce-scatter (jobs 0..2) ----
    auto mv6 = [&](const float* arr, int wo, int redbase) {
        const int qh = (tid >> 5) & 1;
        const int rowoff = 8 * qh;
        const bool b0 = (ks & 1), b1 = (ks & 2), b3 = (ks & 8), b4 = (ks & 16);
        const float* base = arr + (cs & 1) * (256 * 20);
        float acc[6][8];
        #pragma unroll
        for (int f = 0; f < 6; ++f)
            #pragma unroll
            for (int i = 0; i < 8; ++i) acc[f][i] = 0.f;
        #pragma unroll
        for (int kk = 0; kk < 8; ++kk) {
            const float* p = base + (kk * 32 + ks) * 20 + rowoff;
            float4 v0 = *(const float4*)p;
            float4 v1 = *(const float4*)(p + 4);
            #pragma unroll
            for (int f = 0; f < 6; ++f) {
                float wv = w[f][wo + kk];
                acc[f][0] += wv * v0.x; acc[f][1] += wv * v0.y;
                acc[f][2] += wv * v0.z; acc[f][3] += wv * v0.w;
                acc[f][4] += wv * v1.x; acc[f][5] += wv * v1.y;
                acc[f][6] += wv * v1.z; acc[f][7] += wv * v1.w;
            }
        }
        float a[6];
        #pragma unroll
        for (int f = 0; f < 6; ++f) {
            float t[4];
            #pragma unroll
            for (int j = 0; j < 4; ++j) {
                float give = b0 ? acc[f][j] : acc[f][j + 4];
                float recv = dppmov<DPP_XOR1>(give);
                float keep = b0 ? acc[f][j + 4] : acc[f][j];
                t[j] = keep + recv;
            }
            float u[2];
            #pragma unroll
            for (int j = 0; j < 2; ++j) {
                float give = b1 ? t[j] : t[j + 2];
                float recv = dppmov<DPP_XOR2>(give);
                float keep = b1 ? t[j + 2] : t[j];
                u[j] = keep + recv;
            }
            float give = b3 ? u[0] : u[1];
            float recv = dppmov<DPP_XOR8>(give);
            float keep = b3 ? u[1] : u[0];
            a[f] = keep + recv;
        }
        #pragma unroll
        for (int f = 0; f < 6; ++f) a[f] += swzf<SWZ_XOR4>(a[f]);
        float r[3];
        #pragma unroll
        for (int i = 0; i < 3; ++i) {
            float give = b4 ? a[i] : a[i + 3];
            float recv = swzf<SWZ_XOR16>(give);
            float keep = b4 ? a[i + 3] : a[i];
            r[i] = keep + recv;
        }
        if (!(ks & 4)) {
            int bl = ((ks & 1) << 2) | (ks & 2) | ((ks >> 3) & 1);
            int bb = ((tid >> 5) & 1) * 8 + bl;
            int fb3 = ((ks >> 4) & 1) * 3;
            #pragma unroll
            for (int i = 0; i < 3; ++i) {
                int f = fb3 + i, g = f >> 1, c = f & 1;
                red[redbase + (cs & 1) * 384 + g * 128 + ((cs >> 1) * 2 + c) * 16 + bb] = r[i];
            }
        }
    };

    // ---- 4-col matvec + reduce-scatter (jobs 3/4, 32 cols/block, 16 kk) ----
    auto mv4 = [&](const float* arr) {
        const int qh = (tid >> 5) & 1;
        const int rowoff = 8 * qh;
        const bool b0 = (ks & 1), b1 = (ks & 2), b3 = (ks & 8), b4 = (ks & 16);
        float acc[4][8];
        #pragma unroll
        for (int f = 0; f < 4; ++f)
            #pragma unroll
            for (int i = 0; i < 8; ++i) acc[f][i] = 0.f;
        #pragma unroll
        for (int kk = 0; kk < 16; ++kk) {
            const float* p = arr + (kk * 32 + ks) * 20 + rowoff;
            float4 v0 = *(const float4*)p;
            float4 v1 = *(const float4*)(p + 4);
            #pragma unroll
            for (int f = 0; f < 4; ++f) {
                float wv = w[f][kk];
                acc[f][0] += wv * v0.x; acc[f][1] += wv * v0.y;
                acc[f][2] += wv * v0.z; acc[f][3] += wv * v0.w;
                acc[f][4] += wv * v1.x; acc[f][5] += wv * v1.y;
                acc[f][6] += wv * v1.z; acc[f][7] += wv * v1.w;
            }
        }
        float a[4];
        #pragma unroll
        for (int f = 0; f < 4; ++f) {
            float t[4];
            #pragma unroll
            for (int j = 0; j < 4; ++j) {
                float give = b0 ? acc[f][j] : acc[f][j + 4];
                float recv = dppmov<DPP_XOR1>(give);
                float keep = b0 ? acc[f][j + 4] : acc[f][j];
                t[j] = keep + recv;
            }
            float u[2];
            #pragma unroll
            for (int j = 0; j < 2; ++j) {
                float give = b1 ? t[j] : t[j + 2];
                float recv = dppmov<DPP_XOR2>(give);
                float keep = b1 ? t[j + 2] : t[j];
                u[j] = keep + recv;
            }
            float give = b3 ? u[0] : u[1];
            float recv = dppmov<DPP_XOR8>(give);
            float keep = b3 ? u[1] : u[0];
            a[f] = keep + recv;
        }
        #pragma unroll
        for (int f = 0; f < 4; ++f) a[f] += swzf<SWZ_XOR4>(a[f]);
        float r[2];
        #pragma unroll
        for (int i = 0; i < 2; ++i) {
            float give = b4 ? a[i] : a[i + 2];
            float recv = swzf<SWZ_XOR16>(give);
            float keep = b4 ? a[i + 2] : a[i];
            r[i] = keep + recv;
        }
        if (!(ks & 4)) {
            int bl = ((ks & 1) << 2) | (ks & 2) | ((ks >> 3) & 1);
            int bb = ((tid >> 5) & 1) * 8 + bl;
            int f2 = ((ks >> 4) & 1) * 2;
            #pragma unroll
            for (int i = 0; i < 2; ++i)
                red[(cs * 4 + f2 + i) * 16 + bb] = r[i];
        }
    };

    for (int s = 0; s < 102; ++s) {
        const int rp = (s + 2) % 3, wp = s % 3;      // rp = (s-1)%3: 1-back parity
        const unsigned expb = (unsigned)((s + 1) & 1);
        const unsigned myb  = (unsigned)(s & 1);
        int act;
        if      (job == 0) act = (s <= 95);
        else if (job == 1) act = (s >= 2 && s <= 97);
        else if (job == 2) act = (s >= 4 && s <= 99);
        else if (job == 3) act = (s >= 5 && s <= 100);
        else               act = (s >= 6 && s <= 101);
        const int s0 = (job == 1) ? 2 : 4;
        const int dox = (job == 1 || job == 2) && (s >= s0 - 1) && (s <= s0 + 94);
        float* rbuf = (s & 1) ? sx2 : sx;            // x read at step s
        float* wbuf = (s & 1) ? sx : sx2;            // x staged for step s+1
        bool posted = false;

        if (act) {
            // ---- speculative anti-dep: issue 2 flag dwords, no wait ----
            unsigned fv0 = 0xFFFFFFFFu, fv1 = 0xFFFFFFFFu;
            const bool needchk = (tid < 64) && (s >= 2);
            if (needchk)
                ld_coh_u32x2_issue(&flags[fidl[0]], &flags[fidl[1]], fv0, fv1);

            if (job == 1 || job == 2) {
                const float* srcH = ws + WS_STATE(job, rp);
                const float* srcX = ws + WS_STATE(job - 1, rp);
                mv6(rbuf, 0, 0);
                if (dox)
                    stage64k(srcH, srcX, expb, sh, wbuf);
                else
                    stage32k(srcH, expb, sh);
                if (needchk) { vm_wait0(); flagchk(fv0, fv1, (unsigned)(s - 1)); }
                __syncthreads();
                if (tid == 0) st_coh_u32(&flags[bid], (unsigned)(s + 1));
                posted = true;
                mv6(sh, 8, 768);
                __syncthreads();
                if (tid < 128) {
                    int b = tid & 15, jc = jbase + (tid >> 4);
                    int o = tid;
                    float gi0 = red[o]        + red[384 + o];
                    float gi1 = red[128 + o]  + red[512 + o];
                    float gi2 = red[256 + o]  + red[640 + o];
                    float gh0 = red[768 + o]  + red[1152 + o];
                    float gh1 = red[896 + o]  + red[1280 + o];
                    float gh2 = red[1024 + o] + red[1408 + o];
                    float r  = sigm_(gi0 + c_bi0 + gh0 + c_bh0);
                    float zg = sigm_(gi1 + c_bi1 + gh1 + c_bh1);
                    float n  = tanhf(gi2 + c_bi2 + r * (gh2 + c_bh2));
                    float hn = (1.f - zg) * n + zg * hp;
                    hp = hn;
                    st_coh1(&ws[WS_STATE(job, wp) + jc * 16 + b], stampf(hn, myb));
                }
            } else if (job == 0) {
                stage32k(ws + WS_STATE(0, rp), expb, sx);
                if (needchk) { vm_wait0(); flagchk(fv0, fv1, (unsigned)(s - 1)); }
                __syncthreads();
                if (tid == 0) st_coh_u32(&flags[bid], (unsigned)(s + 1));
                posted = true;
                mv6(sx, 8, 768);
                __syncthreads();
                if (tid < 128) {
                    int b = tid & 15, jc = jbase + (tid >> 4);
                    int o = tid;
                    float g0 = red[768 + o]  + red[1152 + o];
                    float g1 = red[896 + o]  + red[1280 + o];
                    float g2 = red[1024 + o] + red[1408 + o];
                    float r  = sigm_(c_bi0 + g0 + c_bh0);
                    float zg = sigm_(c_bi1 + g1 + c_bh1);
                    float n  = tanhf(c_bi2 + r * (g2 + c_bh2));
                    float hn = (1.f - zg) * n + zg * hp;
                    hp = hn;
                    st_coh1(&ws[WS_STATE(0, wp) + jc * 16 + b], stampf(hn, myb));
                }
            } else {
                const float* srcp = (job == 3) ? (ws + WS_STATE(2, rp))
                                               : (ws + WS_A1(rp));
                stage32k(srcp, expb, sx);
                if (needchk) { vm_wait0(); flagchk(fv0, fv1, (unsigned)(s - 1)); }
                __syncthreads();
                if (tid == 0) st_coh_u32(&flags[bid], (unsigned)(s + 1));
                posted = true;
                mv4(sx);
                __syncthreads();
                if (job == 3) {
                    int b = tid & 15, j2 = tid >> 4, jc = jbase + j2;
                    float v = red[j2 * 16 + b] + c_ba;
                    st_coh1(&ws[WS_A1(wp) + jc * 16 + b], stampf(fmaxf(v, 0.f), myb));
                } else {
                    // job4: publish atoms with stamp LSB=1 (consumed by job5)
                    int j2 = tid & 31, b = tid >> 5, jc = jbase + j2;
                    float v = red[j2 * 16 + b] + c_ba;
                    st_coh1(&ws[WS_ATOMS + ((size_t)(s - 6) * 16 + b) * H + jc],
                            stampf(v, 1u));
                }
            }
        } else if (dox) {
            stage32k(ws + WS_STATE(job - 1, rp), expb, wbuf);
        }

        __syncthreads();
        if (!posted && tid == 0) st_coh_u32(&flags[bid], (unsigned)(s + 1));
    }
}

// ---------------- fused edge MLP: relu(e_i + e_j) @ Wb2 + bb2, diag zeroed ----
extern "C" __global__ __launch_bounds__(256)
void k_edge(const float* __restrict__ Wb2, const float* __restrict__ bb2,
            const float* __restrict__ ws, float* __restrict__ out)
{
    __shared__ float ls[32][260];
    __shared__ float wsm[2048];
    const int bid = blockIdx.x;                // b*36 + it*6 + jt
    const int b = bid / 36, r6 = bid % 36, it = r6 / 6, jt = r6 % 6;
    const int tid = threadIdx.x;
    const int ip = tid & 15, jp = tid >> 4;
    float acc0 = 0, acc1 = 0, acc2 = 0, acc3 = 0;

    for (int f = tid; f < 2048; f += 256)      // Wb2 -> LDS (one-time)
        wsm[f] = Wb2[f];

    for (int ph = 0; ph < 2; ++ph) {
        __syncthreads();
        for (int f = tid; f < 2048; f += 256) {
            int r = f >> 6, c4 = f & 63;
            const float* src = (r < 16)
                ? ws + WS_E + ((size_t)b * 96 + it * 16 + r) * H
                : ws + WS_E + ((size_t)(16 + b) * 96 + jt * 16 + (r - 16)) * H;
            float4 v = *(const float4*)(src + ph * 256 + c4 * 4);
            *(float4*)&ls[r][c4 * 4] = v;
        }
        __syncthreads();
        const float* wb = &wsm[ph * 1024];
        #pragma unroll 2
        for (int hh = 0; hh < 256; hh += 4) {
            float4 ei = *(const float4*)&ls[ip][hh];
            float4 ej = *(const float4*)&ls[16 + jp][hh];
            float4 w0 = *(const float4*)(wb + (size_t)hh * 4);
            float4 w1 = *(const float4*)(wb + (size_t)hh * 4 + 4);
            float4 w2 = *(const float4*)(wb + (size_t)hh * 4 + 8);
            float4 w3 = *(const float4*)(wb + (size_t)hh * 4 + 12);
            float v;
            v = fmaxf(ei.x + ej.x, 0.f); acc0 += v * w0.x; acc1 += v * w0.y; acc2 += v * w0.z; acc3 += v * w0.w;
            v = fmaxf(ei.y + ej.y, 0.f); acc0 += v * w1.x; acc1 += v * w1.y; acc2 += v * w1.z; acc3 += v * w1.w;
            v = fmaxf(ei.z + ej.z, 0.f); acc0 += v * w2.x; acc1 += v * w2.y; acc2 += v * w2.z; acc3 += v * w2.w;
            v = fmaxf(ei.w + ej.w, 0.f); acc0 += v * w3.x; acc1 += v * w3.y; acc2 += v * w3.z; acc3 += v * w3.w;
        }
    }
    const int i = it * 16 + ip, j = jt * 16 + jp;
    float4 o;
    if (i == j) { o.x = 0.f; o.y = 0.f; o.z = 0.f; o.w = 0.f; }
    else { o.x = acc0 + bb2[0]; o.y = acc1 + bb2[1]; o.z = acc2 + bb2[2]; o.w = acc3 + bb2[3]; }
    *(float4*)(out + 1536 + (((size_t)b * 96 + i) * 96 + j) * 4) = o;
}

// ---------------- host ----------------
extern "C" void kernel_launch(void* const* d_in, const int* in_sizes, int n_in,
                              void* d_out, int out_size, void* d_ws, size_t ws_size,
                              hipStream_t stream)
{
    const float* z    = (const float*)d_in[0];
    const float* Wl2h = (const float*)d_in[1];
    const float* bl2h = (const float*)d_in[2];
    const float* W_ih = (const float*)d_in[3];
    const float* W_hh = (const float*)d_in[4];
    const float* b_ih = (const float*)d_in[5];
    const float* b_hh = (const float*)d_in[6];
    const float* Wa1  = (const float*)d_in[7];
    const float* ba1  = (const float*)d_in[8];
    const float* Wa2  = (const float*)d_in[9];
    const float* ba2  = (const float*)d_in[10];
    const float* Wb1  = (const float*)d_in[11];
    const float* bb1  = (const float*)d_in[12];
    const float* Wb2  = (const float*)d_in[13];
    const float* bb2  = (const float*)d_in[14];
    float* out = (float*)d_out;
    float* ws  = (float*)d_ws;

    hipLaunchKernelGGL(k_init, dim3(256), dim3(256), 0, stream, z, Wl2h, bl2h, ws);

    // grid 256 = 224 pipeline blocks + 32 streamed eij/argmax workers;
    // 1 block/CU by LDS -> all co-resident, core blocks dispatched first.
    hipLaunchKernelGGL(k_gru, dim3(GRID), dim3(512), 0, stream,
                       W_ih, W_hh, b_ih, b_hh, Wa1, ba1, Wa2, ba2,
                       Wb1, bb1, ws, out);

    hipLaunchKernelGGL(k_edge, dim3(576), dim3(256), 0, stream, Wb2, bb2, ws, out);
}

// Round 12
// 705.128 us; speedup vs baseline: 1.7489x; 1.3391x over previous
//
#include <hip/hip_runtime.h>
#include <math.h>

#define H    512
#define TH3  1536
#define GRID 224

// ---------------- workspace layout (float offsets), P=3 parities ----------------
#define WS_STATE(l,p) ((size_t)((l)*3+(p)) * 8192)          // 0 .. 73728
#define WS_A1(p)      ((size_t)73728 + (size_t)(p)*8192)    // 73728 .. 98304
#define WS_ATOMS      ((size_t)98304)                        // 98304 .. 884736
#define WS_E          ((size_t)884736)                       // e_i/e_j buffers
// flags u32[256] at WS_E during k_gru; k_eij overwrites the region afterwards.

__device__ __forceinline__ float sigm_(float x) { return 1.0f / (1.0f + expf(-x)); }

// ---- LSB stamping: freshness tag lives in the data mantissa LSB ----
__device__ __forceinline__ float stampf(float x, unsigned b) {
    return __uint_as_float((__float_as_uint(x) & ~1u) | b);
}
__device__ __forceinline__ int lsb4ok(float4 v, unsigned e) {
    return ((__float_as_uint(v.x) & 1u) == e) & ((__float_as_uint(v.y) & 1u) == e) &
           ((__float_as_uint(v.z) & 1u) == e) & ((__float_as_uint(v.w) & 1u) == e);
}

// ---- coherent memory helpers (sc0 sc1) ----
__device__ __forceinline__ void ld_coh4(const float* p0, const float* p1,
                                        const float* p2, const float* p3,
                                        float4& a, float4& b, float4& c, float4& d)
{
    asm volatile(
        "global_load_dwordx4 %0, %4, off sc0 sc1\n\t"
        "global_load_dwordx4 %1, %5, off sc0 sc1\n\t"
        "global_load_dwordx4 %2, %6, off sc0 sc1\n\t"
        "global_load_dwordx4 %3, %7, off sc0 sc1\n\t"
        "s_waitcnt vmcnt(0)"
        : "=&v"(a), "=&v"(b), "=&v"(c), "=&v"(d)
        : "v"(p0), "v"(p1), "v"(p2), "v"(p3)
        : "memory");
}

__device__ __forceinline__ void ld_coh8(const float* p0, const float* p1,
                                        const float* p2, const float* p3,
                                        const float* p4, const float* p5,
                                        const float* p6, const float* p7,
                                        float4& a, float4& b, float4& c, float4& d,
                                        float4& e, float4& f, float4& g, float4& h)
{
    asm volatile(
        "global_load_dwordx4 %0, %8, off sc0 sc1\n\t"
        "global_load_dwordx4 %1, %9, off sc0 sc1\n\t"
        "global_load_dwordx4 %2, %10, off sc0 sc1\n\t"
        "global_load_dwordx4 %3, %11, off sc0 sc1\n\t"
        "global_load_dwordx4 %4, %12, off sc0 sc1\n\t"
        "global_load_dwordx4 %5, %13, off sc0 sc1\n\t"
        "global_load_dwordx4 %6, %14, off sc0 sc1\n\t"
        "global_load_dwordx4 %7, %15, off sc0 sc1\n\t"
        "s_waitcnt vmcnt(0)"
        : "=&v"(a), "=&v"(b), "=&v"(c), "=&v"(d),
          "=&v"(e), "=&v"(f), "=&v"(g), "=&v"(h)
        : "v"(p0), "v"(p1), "v"(p2), "v"(p3),
          "v"(p4), "v"(p5), "v"(p6), "v"(p7)
        : "memory");
}

// waitcnt + sched_barrier (rule-#18): pins subsequent register-only consumers
// below the wait; no tied operands (gfx950 rejects tied 128-bit inline asm).
__device__ __forceinline__ void vm_wait0() {
    asm volatile("s_waitcnt vmcnt(0)" ::: "memory");
    __builtin_amdgcn_sched_barrier(0);
}

__device__ __forceinline__ void st_coh1(float* p, float v) {
    asm volatile("global_store_dword %0, %1, off sc0 sc1" :: "v"(p), "v"(v) : "memory");
}

__device__ __forceinline__ void ld_coh_u32x2(const unsigned* p0, const unsigned* p1,
                                             unsigned& a, unsigned& b)
{
    asm volatile(
        "global_load_dword %0, %2, off sc0 sc1\n\t"
        "global_load_dword %1, %3, off sc0 sc1\n\t"
        "s_waitcnt vmcnt(0)"
        : "=&v"(a), "=&v"(b)
        : "v"(p0), "v"(p1)
        : "memory");
}

// issue-only flag loads: fly across the stage; its vmcnt(0) drains them.
__device__ __forceinline__ void ld_coh_u32x2_issue(const unsigned* p0, const unsigned* p1,
                                                   unsigned& a, unsigned& b)
{
    asm volatile(
        "global_load_dword %0, %2, off sc0 sc1\n\t"
        "global_load_dword %1, %3, off sc0 sc1"
        : "=&v"(a), "=&v"(b)
        : "v"(p0), "v"(p1)
        : "memory");
}

__device__ __forceinline__ void st_coh_u32(unsigned* p, unsigned v) {
    asm volatile("global_store_dword %0, %1, off sc0 sc1" :: "v"(p), "v"(v) : "memory");
}

// ---- cross-lane helpers: DPP (VALU) for xor1/xor2/xor8, ds_swizzle for xor4/xor16 ----
template<int CTRL>
__device__ __forceinline__ float dppmov(float v) {
    return __int_as_float(__builtin_amdgcn_update_dpp(
        0, __float_as_int(v), CTRL, 0xF, 0xF, true));
}
#define DPP_XOR1 0xB1   // quad_perm(1,0,3,2)
#define DPP_XOR2 0x4E   // quad_perm(2,3,0,1)
#define DPP_XOR8 0x128  // row_ror:8  (== xor8 within 16)

template<int PAT>
__device__ __forceinline__ float swzf(float v) {
    return __int_as_float(__builtin_amdgcn_ds_swizzle(__float_as_int(v), PAT));
}
#define SWZ_XOR4  0x101F
#define SWZ_XOR16 0x401F

// ---------------- h_init: z @ W_l2h + b_l2h, LSB-stamped parities ----------------
// 256 blocks, 8-way K-split + LDS reduce (parallel version, proven R9-R11).
// Skews 0/2/4/5/6 => first reads: STATE0 real@p2, STATE1 real@p1, STATE2 real@p0,
// all with expected LSB 1; junk parities carry the complement of their first
// expected LSB so consumers spin until the first fresh write lands.
extern "C" __global__ __launch_bounds__(256)
void k_init(const float* __restrict__ z, const float* __restrict__ Wl2h,
            const float* __restrict__ bl2h, float* __restrict__ ws)
{
    __shared__ float part[8][2][16];
    if (blockIdx.x == 0)
        ((unsigned*)(ws + WS_E))[threadIdx.x] = 0u;   // flags[0..255]
    const int t  = threadIdx.x;
    const int b  = t & 15, j2 = (t >> 4) & 1, kq = t >> 5;   // kq 0..7
    const int j  = blockIdx.x * 2 + j2;
    float acc = 0.f;
    const int k0 = kq * 64;
    #pragma unroll 8
    for (int k = 0; k < 64; ++k)
        acc += z[b * H + k0 + k] * Wl2h[(size_t)(k0 + k) * H + j];
    part[kq][j2][b] = acc;
    __syncthreads();
    if (t < 32) {
        float a = bl2h[j];
        #pragma unroll
        for (int q = 0; q < 8; ++q) a += part[q][j2][b];

        const int preh[3][3] = { { 1, 0, -1 },
                                 { 0, -1, 1 },
                                 { -1, 1, 0 } };
        #pragma unroll
        for (int l = 0; l < 3; ++l)
            #pragma unroll
            for (int p = 0; p < 3; ++p) {
                float v = (preh[l][p] < 0) ? stampf(a, 1u)
                                           : __uint_as_float((unsigned)preh[l][p]);
                ws[WS_STATE(l, p) + j * 16 + b] = v;
            }
        const unsigned preA1[3] = { 1u, 0u, 0u };
        #pragma unroll
        for (int p = 0; p < 3; ++p)
            ws[WS_A1(p) + j * 16 + b] = __uint_as_float(preA1[p]);
    }
}

// ---------------- persistent pipelined GRU + MLP decoder ----------------
// 224 blocks, 1/CU by LDS (126 KB). Stage map (skew in parens):
//   job0 (0): bid   0..63,  8 cols, h@W_hh K-split over cs&1    -> STATE0
//   job1 (2): bid  64..127, 8 cols, phase A x@W_ih / B h@W_hh   -> STATE1
//   job2 (4): bid 128..191, 8 cols, phase A / B                 -> STATE2
//   job3 (5): bid 192..207, 32 cols, relu(h2@Wa1+ba1)           -> A1
//   job4 (6): bid 208..223, 32 cols, a1@Wa2+ba2                 -> atoms
// R6 configuration (proven 556us k_gru / 734us total — best verified):
// fused detect-with-fetch after phase A, speculative flag loads checked
// before the first barrier, early flag post, plain sc0sc1 state stores.
// Concurrency experiments all reverted: fence (R9, -2x), atomics (R7, neg),
// co-run streamed tail (R10/R11, -60% on core) — the recurrence period is
// fabric-latency (tau_vis ~3.6us) bound and taxed by ANY co-resident traffic.
__global__ __launch_bounds__(512, 2)
void k_gru(const float* __restrict__ W_ih, const float* __restrict__ W_hh,
           const float* __restrict__ b_ih, const float* __restrict__ b_hh,
           const float* __restrict__ Wa1,  const float* __restrict__ ba1,
           const float* __restrict__ Wa2,  const float* __restrict__ ba2,
           float* __restrict__ ws)
{
    __shared__ float sx[10240];
    __shared__ float sx2[10240];
    __shared__ float sh[10240];
    __shared__ float red[1536];
    unsigned* flags = (unsigned*)(ws + WS_E);

    const int bid = blockIdx.x;
    const int tid = threadIdx.x;

    int job, jbase;
    if      (bid < 64)  { job = 0; jbase = bid * 8; }
    else if (bid < 128) { job = 1; jbase = (bid - 64) * 8; }
    else if (bid < 192) { job = 2; jbase = (bid - 128) * 8; }
    else if (bid < 208) { job = 3; jbase = (bid - 192) * 32; }
    else                { job = 4; jbase = (bid - 208) * 32; }

    const int ks = tid & 31;
    const int cs = tid >> 6;

    // ---- anti-dep poll set: consumers of the buffer this stage writes ----
    int rs0, rc0;
    if      (job == 0) { rs0 = 0;   rc0 = 128; }
    else if (job == 1) { rs0 = 64;  rc0 = 128; }
    else if (job == 2) { rs0 = 128; rc0 = 80;  }
    else if (job == 3) { rs0 = 208; rc0 = 16;  }
    else               { rs0 = 0;   rc0 = 0;   }
    int fidl[2];
    #pragma unroll
    for (int e = 0; e < 2; ++e) {
        int idx = (tid & 63) + e * 64;
        fidl[e] = (idx < rc0) ? rs0 + idx : bid;   // own flag trivially passes
    }

    // ---- one-time weight preload into registers ----
    float w[6][16];
    if (job <= 2) {
        const int khalf = cs & 1, cpair = cs >> 1;
        const int colbase = jbase + cpair * 2;
        const float* WB = W_hh + (size_t)job * H * TH3;
        const float* WA = W_ih + (size_t)job * H * TH3;
        #pragma unroll
        for (int f = 0; f < 6; ++f) {
            int g = f >> 1, c = f & 1;
            #pragma unroll
            for (int kk = 0; kk < 8; ++kk) {
                size_t ro = (size_t)(khalf * 256 + kk * 32 + ks) * TH3 + g * 512 + colbase + c;
                w[f][8 + kk] = WB[ro];
                if (job != 0) w[f][kk] = WA[ro];
            }
        }
    } else {
        const float* base = (job == 3) ? Wa1 : Wa2;
        const int colbase = jbase + cs * 4;
        #pragma unroll
        for (int f = 0; f < 4; ++f)
            #pragma unroll
            for (int kk = 0; kk < 16; ++kk)
                w[f][kk] = base[(size_t)(kk * 32 + ks) * H + colbase + f];
    }

    // ---- epilogue constants (biases + running h for own cols) ----
    float c_bi0 = 0, c_bi1 = 0, c_bi2 = 0, c_bh0 = 0, c_bh1 = 0, c_bh2 = 0;
    float hp = 0.f, c_ba = 0.f;
    if (job <= 2) {
        if (tid < 128) {
            int b = tid & 15, j2 = tid >> 4, jc = jbase + j2;
            const float* bi  = b_ih + (size_t)job * TH3;
            const float* bhh = b_hh + (size_t)job * TH3;
            c_bi0 = bi[jc]; c_bi1 = bi[512 + jc]; c_bi2 = bi[1024 + jc];
            c_bh0 = bhh[jc]; c_bh1 = bhh[512 + jc]; c_bh2 = bhh[1024 + jc];
            const int hpp = (job == 0) ? 2 : (job == 1) ? 1 : 0;  // init-real parity
            hp = ws[WS_STATE(job, hpp) + jc * 16 + b];
        }
    } else if (job == 3) {
        c_ba = ba1[jbase + (tid >> 4)];
    } else {
        c_ba = ba2[jbase + (tid & 31)];
    }

    // ---- verify+stage one 32KB [512][16] buffer into LDS [512][20] (fused) ----
    auto stage32k = [&](const float* src, unsigned eb, float* dst) {
        const int k0 = tid >> 2, q4 = (tid & 3) * 4;
        float4 a, b, c, d;
        for (;;) {
            ld_coh4(src + 4 * tid, src + 4 * (tid + 512),
                    src + 4 * (tid + 1024), src + 4 * (tid + 1536), a, b, c, d);
            if (__all(lsb4ok(a, eb) & lsb4ok(b, eb) & lsb4ok(c, eb) & lsb4ok(d, eb)))
                break;
            __builtin_amdgcn_s_sleep(1);
        }
        *(float4*)&dst[(k0      ) * 20 + q4] = a;
        *(float4*)&dst[(k0 + 128) * 20 + q4] = b;
        *(float4*)&dst[(k0 + 256) * 20 + q4] = c;
        *(float4*)&dst[(k0 + 384) * 20 + q4] = d;
    };

    // ---- verify+stage TWO 32KB buffers in ONE round trip (jobs 1/2) ----
    // srcH = own h (this step, may spin); srcX = next-step x (1 step old, fresh)
    auto stage64k = [&](const float* srcH, const float* srcX, unsigned eb,
                        float* dstH, float* dstX) {
        const int k0 = tid >> 2, q4 = (tid & 3) * 4;
        float4 xa, xb, xc, xd, ha, hb, hc, hd;
        for (;;) {
            ld_coh8(srcX + 4 * tid, srcX + 4 * (tid + 512),
                    srcX + 4 * (tid + 1024), srcX + 4 * (tid + 1536),
                    srcH + 4 * tid, srcH + 4 * (tid + 512),
                    srcH + 4 * (tid + 1024), srcH + 4 * (tid + 1536),
                    xa, xb, xc, xd, ha, hb, hc, hd);
            int ok = lsb4ok(xa, eb) & lsb4ok(xb, eb) & lsb4ok(xc, eb) & lsb4ok(xd, eb) &
                     lsb4ok(ha, eb) & lsb4ok(hb, eb) & lsb4ok(hc, eb) & lsb4ok(hd, eb);
            if (__all(ok)) break;
            __builtin_amdgcn_s_sleep(1);
        }
        *(float4*)&dstX[(k0      ) * 20 + q4] = xa;
        *(float4*)&dstX[(k0 + 128) * 20 + q4] = xb;
        *(float4*)&dstX[(k0 + 256) * 20 + q4] = xc;
        *(float4*)&dstX[(k0 + 384) * 20 + q4] = xd;
        *(float4*)&dstH[(k0      ) * 20 + q4] = ha;
        *(float4*)&dstH[(k0 + 128) * 20 + q4] = hb;
        *(float4*)&dstH[(k0 + 256) * 20 + q4] = hc;
        *(float4*)&dstH[(k0 + 384) * 20 + q4] = hd;
    };

    // ---- speculative flag check: values were issued at step top and drained
    //      by the stage's vmcnt(0); compare is free. Spin only on stale miss.
    auto flagchk = [&](unsigned fv0, unsigned fv1, unsigned lim) {
        if (!__all((int)((fv0 >= lim) & (fv1 >= lim)))) {
            for (;;) {
                __builtin_amdgcn_s_sleep(1);
                unsigned v0, v1;
                ld_coh_u32x2(&flags[fidl[0]], &flags[fidl[1]], v0, v1);
                if (__all((int)((v0 >= lim) & (v1 >= lim)))) break;
            }
        }
    };

    // ---- K-split 6-gate matvec + reduce-scatter (jobs 0..2) ----
    auto mv6 = [&](const float* arr, int wo, int redbase) {
        const int qh = (tid >> 5) & 1;
        const int rowoff = 8 * qh;
        const bool b0 = (ks & 1), b1 = (ks & 2), b3 = (ks & 8), b4 = (ks & 16);
        const float* base = arr + (cs & 1) * (256 * 20);
        float acc[6][8];
        #pragma unroll
        for (int f = 0; f < 6; ++f)
            #pragma unroll
            for (int i = 0; i < 8; ++i) acc[f][i] = 0.f;
        #pragma unroll
        for (int kk = 0; kk < 8; ++kk) {
            const float* p = base + (kk * 32 + ks) * 20 + rowoff;
            float4 v0 = *(const float4*)p;
            float4 v1 = *(const float4*)(p + 4);
            #pragma unroll
            for (int f = 0; f < 6; ++f) {
                float wv = w[f][wo + kk];
                acc[f][0] += wv * v0.x; acc[f][1] += wv * v0.y;
                acc[f][2] += wv * v0.z; acc[f][3] += wv * v0.w;
                acc[f][4] += wv * v1.x; acc[f][5] += wv * v1.y;
                acc[f][6] += wv * v1.z; acc[f][7] += wv * v1.w;
            }
        }
        float a[6];
        #pragma unroll
        for (int f = 0; f < 6; ++f) {
            float t[4];
            #pragma unroll
            for (int j = 0; j < 4; ++j) {
                float give = b0 ? acc[f][j] : acc[f][j + 4];
                float recv = dppmov<DPP_XOR1>(give);
                float keep = b0 ? acc[f][j + 4] : acc[f][j];
                t[j] = keep + recv;
            }
            float u[2];
            #pragma unroll
            for (int j = 0; j < 2; ++j) {
                float give = b1 ? t[j] : t[j + 2];
                float recv = dppmov<DPP_XOR2>(give);
                float keep = b1 ? t[j + 2] : t[j];
                u[j] = keep + recv;
            }
            float give = b3 ? u[0] : u[1];
            float recv = dppmov<DPP_XOR8>(give);
            float keep = b3 ? u[1] : u[0];
            a[f] = keep + recv;
        }
        #pragma unroll
        for (int f = 0; f < 6; ++f) a[f] += swzf<SWZ_XOR4>(a[f]);
        float r[3];
        #pragma unroll
        for (int i = 0; i < 3; ++i) {
            float give = b4 ? a[i] : a[i + 3];
            float recv = swzf<SWZ_XOR16>(give);
            float keep = b4 ? a[i + 3] : a[i];
            r[i] = keep + recv;
        }
        if (!(ks & 4)) {
            int bl = ((ks & 1) << 2) | (ks & 2) | ((ks >> 3) & 1);
            int bb = ((tid >> 5) & 1) * 8 + bl;
            int fb3 = ((ks >> 4) & 1) * 3;
            #pragma unroll
            for (int i = 0; i < 3; ++i) {
                int f = fb3 + i, g = f >> 1, c = f & 1;
                red[redbase + (cs & 1) * 384 + g * 128 + ((cs >> 1) * 2 + c) * 16 + bb] = r[i];
            }
        }
    };

    // ---- 4-col matvec + reduce-scatter (jobs 3/4, 32 cols/block, 16 kk) ----
    auto mv4 = [&](const float* arr) {
        const int qh = (tid >> 5) & 1;
        const int rowoff = 8 * qh;
        const bool b0 = (ks & 1), b1 = (ks & 2), b3 = (ks & 8), b4 = (ks & 16);
        float acc[4][8];
        #pragma unroll
        for (int f = 0; f < 4; ++f)
            #pragma unroll
            for (int i = 0; i < 8; ++i) acc[f][i] = 0.f;
        #pragma unroll
        for (int kk = 0; kk < 16; ++kk) {
            const float* p = arr + (kk * 32 + ks) * 20 + rowoff;
            float4 v0 = *(const float4*)p;
            float4 v1 = *(const float4*)(p + 4);
            #pragma unroll
            for (int f = 0; f < 4; ++f) {
                float wv = w[f][kk];
                acc[f][0] += wv * v0.x; acc[f][1] += wv * v0.y;
                acc[f][2] += wv * v0.z; acc[f][3] += wv * v0.w;
                acc[f][4] += wv * v1.x; acc[f][5] += wv * v1.y;
                acc[f][6] += wv * v1.z; acc[f][7] += wv * v1.w;
            }
        }
        float a[4];
        #pragma unroll
        for (int f = 0; f < 4; ++f) {
            float t[4];
            #pragma unroll
            for (int j = 0; j < 4; ++j) {
                float give = b0 ? acc[f][j] : acc[f][j + 4];
                float recv = dppmov<DPP_XOR1>(give);
                float keep = b0 ? acc[f][j + 4] : acc[f][j];
                t[j] = keep + recv;
            }
            float u[2];
            #pragma unroll
            for (int j = 0; j < 2; ++j) {
                float give = b1 ? t[j] : t[j + 2];
                float recv = dppmov<DPP_XOR2>(give);
                float keep = b1 ? t[j + 2] : t[j];
                u[j] = keep + recv;
            }
            float give = b3 ? u[0] : u[1];
            float recv = dppmov<DPP_XOR8>(give);
            float keep = b3 ? u[1] : u[0];
            a[f] = keep + recv;
        }
        #pragma unroll
        for (int f = 0; f < 4; ++f) a[f] += swzf<SWZ_XOR4>(a[f]);
        float r[2];
        #pragma unroll
        for (int i = 0; i < 2; ++i) {
            float give = b4 ? a[i] : a[i + 2];
            float recv = swzf<SWZ_XOR16>(give);
            float keep = b4 ? a[i + 2] : a[i];
            r[i] = keep + recv;
        }
        if (!(ks & 4)) {
            int bl = ((ks & 1) << 2) | (ks & 2) | ((ks >> 3) & 1);
            int bb = ((tid >> 5) & 1) * 8 + bl;
            int f2 = ((ks >> 4) & 1) * 2;
            #pragma unroll
            for (int i = 0; i < 2; ++i)
                red[(cs * 4 + f2 + i) * 16 + bb] = r[i];
        }
    };

    for (int s = 0; s < 102; ++s) {
        const int rp = (s + 2) % 3, wp = s % 3;      // rp = (s-1)%3: 1-back parity
        const unsigned expb = (unsigned)((s + 1) & 1);
        const unsigned myb  = (unsigned)(s & 1);
        int act;
        if      (job == 0) act = (s <= 95);
        else if (job == 1) act = (s >= 2 && s <= 97);
        else if (job == 2) act = (s >= 4 && s <= 99);
        else if (job == 3) act = (s >= 5 && s <= 100);
        else               act = (s >= 6 && s <= 101);
        // jobs 1/2: stage next-step x during this step's phase-B round?
        // x consumed at steps s0..s0+95  ->  staged at s in [s0-1, s0+94]
        const int s0 = (job == 1) ? 2 : 4;
        const int dox = (job == 1 || job == 2) && (s >= s0 - 1) && (s <= s0 + 94);
        float* rbuf = (s & 1) ? sx2 : sx;            // x read at step s
        float* wbuf = (s & 1) ? sx : sx2;            // x staged for step s+1
        bool posted = false;

        if (act) {
            // ---- speculative anti-dep: issue 2 flag dwords, no wait ----
            unsigned fv0 = 0xFFFFFFFFu, fv1 = 0xFFFFFFFFu;
            const bool needchk = (tid < 64) && (s >= 2);
            if (needchk)
                ld_coh_u32x2_issue(&flags[fidl[0]], &flags[fidl[1]], fv0, fv1);

            if (job == 1 || job == 2) {
                const float* srcH = ws + WS_STATE(job, rp);
                const float* srcX = ws + WS_STATE(job - 1, rp);
                // phase A: x @ W_ih from rbuf (staged during step s-1, no wait)
                mv6(rbuf, 0, 0);
                // phase B: fetch own h (+ next-step x) — fused detect (R3 path)
                if (dox)
                    stage64k(srcH, srcX, expb, sh, wbuf);
                else
                    stage32k(srcH, expb, sh);
                // flag check: drained by stage's vmcnt(0); compare ~free
                if (needchk) { vm_wait0(); flagchk(fv0, fv1, (unsigned)(s - 1)); }
                __syncthreads();
                // early anti-dep release: all coherent reads complete here
                if (tid == 0) st_coh_u32(&flags[bid], (unsigned)(s + 1));
                posted = true;
                mv6(sh, 8, 768);
                __syncthreads();
                if (tid < 128) {
                    int b = tid & 15, jc = jbase + (tid >> 4);
                    int o = tid;
                    float gi0 = red[o]        + red[384 + o];
                    float gi1 = red[128 + o]  + red[512 + o];
                    float gi2 = red[256 + o]  + red[640 + o];
                    float gh0 = red[768 + o]  + red[1152 + o];
                    float gh1 = red[896 + o]  + red[1280 + o];
                    float gh2 = red[1024 + o] + red[1408 + o];
                    float r  = sigm_(gi0 + c_bi0 + gh0 + c_bh0);
                    float zg = sigm_(gi1 + c_bi1 + gh1 + c_bh1);
                    float n  = tanhf(gi2 + c_bi2 + r * (gh2 + c_bh2));
                    float hn = (1.f - zg) * n + zg * hp;
                    hp = hn;
                    st_coh1(&ws[WS_STATE(job, wp) + jc * 16 + b], stampf(hn, myb));
                }
            } else if (job == 0) {
                stage32k(ws + WS_STATE(0, rp), expb, sx);
                if (needchk) { vm_wait0(); flagchk(fv0, fv1, (unsigned)(s - 1)); }
                __syncthreads();
                if (tid == 0) st_coh_u32(&flags[bid], (unsigned)(s + 1));
                posted = true;
                mv6(sx, 8, 768);
                __syncthreads();
                if (tid < 128) {
                    int b = tid & 15, jc = jbase + (tid >> 4);
                    int o = tid;
                    float g0 = red[768 + o]  + red[1152 + o];
                    float g1 = red[896 + o]  + red[1280 + o];
                    float g2 = red[1024 + o] + red[1408 + o];
                    float r  = sigm_(c_bi0 + g0 + c_bh0);
                    float zg = sigm_(c_bi1 + g1 + c_bh1);
                    float n  = tanhf(c_bi2 + r * (g2 + c_bh2));
                    float hn = (1.f - zg) * n + zg * hp;
                    hp = hn;
                    st_coh1(&ws[WS_STATE(0, wp) + jc * 16 + b], stampf(hn, myb));
                }
            } else {
                const float* srcp = (job == 3) ? (ws + WS_STATE(2, rp))
                                               : (ws + WS_A1(rp));
                stage32k(srcp, expb, sx);
                if (needchk) { vm_wait0(); flagchk(fv0, fv1, (unsigned)(s - 1)); }
                __syncthreads();
                if (tid == 0) st_coh_u32(&flags[bid], (unsigned)(s + 1));
                posted = true;
                mv4(sx);
                __syncthreads();
                if (job == 3) {
                    int b = tid & 15, j2 = tid >> 4, jc = jbase + j2;
                    float v = red[j2 * 16 + b] + c_ba;
                    st_coh1(&ws[WS_A1(wp) + jc * 16 + b], stampf(fmaxf(v, 0.f), myb));
                } else {
                    int j2 = tid & 31, b = tid >> 5, jc = jbase + j2;
                    float v = red[j2 * 16 + b] + c_ba;
                    ws[WS_ATOMS + ((size_t)(s - 6) * 16 + b) * H + jc] = v;
                }
            }
        } else if (dox) {
            // pre-loop x prestage (s == s0-1 only): fill wbuf for first phase A
            stage32k(ws + WS_STATE(job - 1, rp), expb, wbuf);
        }

        // ---- bottom barrier protects red[]/LDS reuse and barrier pairing;
        //      post flag here only if not already released this step ----
        __syncthreads();
        if (!posted && tid == 0) st_coh_u32(&flags[bid], (unsigned)(s + 1));
    }
}

// ---------------- argmax over logits (first-max-wins) ----------------
extern "C" __global__ __launch_bounds__(256)
void k_argmax(const float* __restrict__ ws, float* __restrict__ out)
{
    const int t = blockIdx.x;                  // 0..95
    const int wv = threadIdx.x >> 6, lane = threadIdx.x & 63;
    for (int b = wv; b < 16; b += 4) {
        const float* row = ws + WS_ATOMS + ((size_t)t * 16 + b) * H;
        float mx = -3.4028235e38f; int mi = 0;
        #pragma unroll
        for (int c = 0; c < 8; ++c) {
            int idx = lane + c * 64;
            float v = row[idx];
            if (v > mx) { mx = v; mi = idx; }
        }
        #pragma unroll
        for (int off = 32; off >= 1; off >>= 1) {
            float omx = __shfl_down(mx, off);
            int   omi = __shfl_down(mi, off);
            if (omx > mx || (omx == mx && omi < mi)) { mx = omx; mi = omi; }
        }
        if (lane == 0) out[b * 96 + t] = (float)mi;
    }
}

// ---------------- e_i / e_j = atoms @ Wb1 halves, tiled (16 rows reuse) -------
extern "C" __global__ __launch_bounds__(256)
void k_eij(const float* __restrict__ Wb1, const float* __restrict__ bb1,
           float* __restrict__ ws)
{
    __shared__ float aT[8192];                 // [k][b16], 32 KB
    const int bid = blockIdx.x;
    const int t = bid >> 4, m = (bid >> 3) & 1, ct = bid & 7;
    const int tid = threadIdx.x;
    const float* atoms = ws + WS_ATOMS;
    for (int f = tid; f < 2048; f += 256) {    // transpose-stage A tile
        int b = f >> 7, kq = f & 127;
        float4 v = ((const float4*)(atoms + ((size_t)(t * 16 + b)) * H))[kq];
        aT[(kq * 4 + 0) * 16 + b] = v.x;
        aT[(kq * 4 + 1) * 16 + b] = v.y;
        aT[(kq * 4 + 2) * 16 + b] = v.z;
        aT[(kq * 4 + 3) * 16 + b] = v.w;
    }
    __syncthreads();
    const int c = tid & 63, rq = tid >> 6;
    const int col = ct * 64 + c;
    const float* Wp = Wb1 + (size_t)m * H * H + col;
    float a0 = 0, a1 = 0, a2 = 0, a3 = 0;
    #pragma unroll 8
    for (int k = 0; k < 512; ++k) {
        float  wv = Wp[(size_t)k * H];
        float4 av = *(const float4*)&aT[k * 16 + rq * 4];
        a0 += av.x * wv; a1 += av.y * wv; a2 += av.z * wv; a3 += av.w * wv;
    }
    float bb = (m == 0) ? bb1[col] : 0.f;
    a0 += bb; a1 += bb; a2 += bb; a3 += bb;
    float* eb = ws + WS_E + (size_t)(m * 16) * 96 * H;
    eb[((size_t)(rq * 4 + 0) * 96 + t) * H + col] = a0;
    eb[((size_t)(rq * 4 + 1) * 96 + t) * H + col] = a1;
    eb[((size_t)(rq * 4 + 2) * 96 + t) * H + col] = a2;
    eb[((size_t)(rq * 4 + 3) * 96 + t) * H + col] = a3;
}

// ---------------- fused edge MLP: relu(e_i + e_j) @ Wb2 + bb2, diag zeroed ----
extern "C" __global__ __launch_bounds__(256)
void k_edge(const float* __restrict__ Wb2, const float* __restrict__ bb2,
            const float* __restrict__ ws, float* __restrict__ out)
{
    __shared__ float ls[32][260];
    __shared__ float wsm[2048];
    const int bid = blockIdx.x;                // b*36 + it*6 + jt
    const int b = bid / 36, r6 = bid % 36, it = r6 / 6, jt = r6 % 6;
    const int tid = threadIdx.x;
    const int ip = tid & 15, jp = tid >> 4;
    float acc0 = 0, acc1 = 0, acc2 = 0, acc3 = 0;

    for (int f = tid; f < 2048; f += 256)      // Wb2 -> LDS (one-time)
        wsm[f] = Wb2[f];

    for (int ph = 0; ph < 2; ++ph) {
        __syncthreads();
        for (int f = tid; f < 2048; f += 256) {
            int r = f >> 6, c4 = f & 63;
            const float* src = (r < 16)
                ? ws + WS_E + ((size_t)b * 96 + it * 16 + r) * H
                : ws + WS_E + ((size_t)(16 + b) * 96 + jt * 16 + (r - 16)) * H;
            float4 v = *(const float4*)(src + ph * 256 + c4 * 4);
            *(float4*)&ls[r][c4 * 4] = v;
        }
        __syncthreads();
        const float* wb = &wsm[ph * 1024];
        #pragma unroll 2
        for (int hh = 0; hh < 256; hh += 4) {
            float4 ei = *(const float4*)&ls[ip][hh];
            float4 ej = *(const float4*)&ls[16 + jp][hh];
            float4 w0 = *(const float4*)(wb + (size_t)hh * 4);
            float4 w1 = *(const float4*)(wb + (size_t)hh * 4 + 4);
            float4 w2 = *(const float4*)(wb + (size_t)hh * 4 + 8);
            float4 w3 = *(const float4*)(wb + (size_t)hh * 4 + 12);
            float v;
            v = fmaxf(ei.x + ej.x, 0.f); acc0 += v * w0.x; acc1 += v * w0.y; acc2 += v * w0.z; acc3 += v * w0.w;
            v = fmaxf(ei.y + ej.y, 0.f); acc0 += v * w1.x; acc1 += v * w1.y; acc2 += v * w1.z; acc3 += v * w1.w;
            v = fmaxf(ei.z + ej.z, 0.f); acc0 += v * w2.x; acc1 += v * w2.y; acc2 += v * w2.z; acc3 += v * w2.w;
            v = fmaxf(ei.w + ej.w, 0.f); acc0 += v * w3.x; acc1 += v * w3.y; acc2 += v * w3.z; acc3 += v * w3.w;
        }
    }
    const int i = it * 16 + ip, j = jt * 16 + jp;
    float4 o;
    if (i == j) { o.x = 0.f; o.y = 0.f; o.z = 0.f; o.w = 0.f; }
    else { o.x = acc0 + bb2[0]; o.y = acc1 + bb2[1]; o.z = acc2 + bb2[2]; o.w = acc3 + bb2[3]; }
    *(float4*)(out + 1536 + (((size_t)b * 96 + i) * 96 + j) * 4) = o;
}

// ---------------- host ----------------
extern "C" void kernel_launch(void* const* d_in, const int* in_sizes, int n_in,
                              void* d_out, int out_size, void* d_ws, size_t ws_size,
                              hipStream_t stream)
{
    const float* z    = (const float*)d_in[0];
    const float* Wl2h = (const float*)d_in[1];
    const float* bl2h = (const float*)d_in[2];
    const float* W_ih = (const float*)d_in[3];
    const float* W_hh = (const float*)d_in[4];
    const float* b_ih = (const float*)d_in[5];
    const float* b_hh = (const float*)d_in[6];
    const float* Wa1  = (const float*)d_in[7];
    const float* ba1  = (const float*)d_in[8];
    const float* Wa2  = (const float*)d_in[9];
    const float* ba2  = (const float*)d_in[10];
    const float* Wb1  = (const float*)d_in[11];
    const float* bb1  = (const float*)d_in[12];
    const float* Wb2  = (const float*)d_in[13];
    const float* bb2  = (const float*)d_in[14];
    float* out = (float*)d_out;
    float* ws  = (float*)d_ws;

    hipLaunchKernelGGL(k_init, dim3(256), dim3(256), 0, stream, z, Wl2h, bl2h, ws);

    // regular launch: grid 224 (1 block/CU by LDS) is co-resident by capacity
    hipLaunchKernelGGL(k_gru, dim3(GRID), dim3(512), 0, stream,
                       W_ih, W_hh, b_ih, b_hh, Wa1, ba1, Wa2, ba2, ws);

    hipLaunchKernelGGL(k_argmax, dim3(96), dim3(256), 0, stream, ws, out);
    hipLaunchKernelGGL(k_eij, dim3(1536), dim3(256), 0, stream, Wb1, bb1, ws);
    hipLaunchKernelGGL(k_edge, dim3(576), dim3(256), 0, stream, Wb2, bb2, ws, out);
}